// Round 13
// baseline (267.449 us; speedup 1.0000x reference)
//
#include <hip/hip_runtime.h>

#define N_NODES 100000
#define N_EDGES 1600000
#define DIN 64
#define DOUT 32
#define NEG_SLOPE 0.01f
#define NBUCK 196          // buckets of 512 nodes (dst >> 9)
#define CH 4096            // edges per binpass1 block
#define NB1 ((N_EDGES + CH - 1) / CH)  // 391
#define NOFS 200           // stride of per-block offs row (196+1 rounded)

__device__ inline unsigned short f2bf(float f) {  // RNE
    unsigned int u = __float_as_uint(f);
    unsigned int r = (u + 0x7fffu + ((u >> 16) & 1u)) >> 16;
    return (unsigned short)r;
}
__device__ inline float bflo(unsigned int p) { return __uint_as_float(p << 16); }
__device__ inline float bfhi(unsigned int p) { return __uint_as_float(p & 0xffff0000u); }
#define NTL(p) __builtin_nontemporal_load(p)

__device__ inline void addpack4(float* a, uint4 r) {
    a[0] += bflo(r.x); a[1] += bfhi(r.x);
    a[2] += bflo(r.y); a[3] += bfhi(r.y);
    a[4] += bflo(r.z); a[5] += bfhi(r.z);
    a[6] += bflo(r.w); a[7] += bfhi(r.w);
}
__device__ inline void addpack2(float* a, uint2 r) {
    a[0] += bflo(r.x); a[1] += bfhi(r.x);
    a[2] += bflo(r.y); a[3] += bfhi(r.y);
}

// ---------------- binning CSR build ----------------
__global__ void zero_bf_kernel(int* __restrict__ bucketfill) {
    if (threadIdx.x < NBUCK) bucketfill[threadIdx.x] = 0;
}

// local counting sort: each block sorts its 4096 edges by bucket into its OWN
// contiguous 16KB staging region (dense, single-writer lines), publishing
// per-block bucket offsets and global bucket totals.
__global__ __launch_bounds__(256) void binpass1_kernel(const int* __restrict__ src,
                                                       const int* __restrict__ dst,
                                                       int* __restrict__ bucketfill,
                                                       int* __restrict__ offs,
                                                       unsigned int* __restrict__ staging) {
    __shared__ int hist[NBUCK];
    __shared__ int base[NBUCK];
    __shared__ int scanbuf[256];
    int tid = threadIdx.x;
    int b = blockIdx.x;
    for (int t = tid; t < NBUCK; t += 256) hist[t] = 0;
    __syncthreads();

    int e0 = b * CH + tid;
    int bk[16];
    int rk[16];
    unsigned int pay[16];
#pragma unroll
    for (int i = 0; i < 16; ++i) {
        int e = e0 + i * 256;
        if (e < N_EDGES) {
            int d = NTL(&dst[e]);
            int s = NTL(&src[e]);
            bk[i] = d >> 9;
            pay[i] = (unsigned int)s | ((unsigned int)(d & 511) << 17);
            rk[i] = atomicAdd(&hist[bk[i]], 1);
        } else {
            bk[i] = -1;
        }
    }
    __syncthreads();
    // exclusive scan of hist -> base; publish offs + global totals
    int v = (tid < NBUCK) ? hist[tid] : 0;
    scanbuf[tid] = v;
    __syncthreads();
    for (int off = 1; off < 256; off <<= 1) {
        int a = scanbuf[tid];
        int add = (tid >= off) ? scanbuf[tid - off] : 0;
        __syncthreads();
        scanbuf[tid] = a + add;
        __syncthreads();
    }
    if (tid < NBUCK) {
        int ex = scanbuf[tid] - v;
        base[tid] = ex;
        offs[b * NOFS + tid] = ex;
        if (v) atomicAdd(&bucketfill[tid], v);
    }
    if (tid == 0) offs[b * NOFS + NBUCK] = (b == NB1 - 1) ? (N_EDGES - (NB1 - 1) * CH) : CH;
    __syncthreads();
    unsigned int* reg = staging + (size_t)b * CH;
#pragma unroll
    for (int i = 0; i < 16; ++i) {
        if (bk[i] >= 0) reg[base[bk[i]] + rk[i]] = pay[i];
    }
}

// per-bucket merge: runs [offs[b][k], offs[b][k+1]) from all 391 block regions.
// node hist -> scan -> rowptr/dinv -> exact CSR placement via LDS cursors.
__global__ __launch_bounds__(256) void binpass2_kernel(const unsigned int* __restrict__ staging,
                                                       const int* __restrict__ bucketfill,
                                                       const int* __restrict__ offs,
                                                       int* __restrict__ rowptr,
                                                       float* __restrict__ dinv,
                                                       int* __restrict__ colsrc) {
    __shared__ int hist[512];
    __shared__ int posl[512];
    __shared__ int psum[256];
    __shared__ int red[4];
    int k = blockIdx.x;
    int tid = threadIdx.x;
    int base_node = k << 9;
    int nn = min(512, N_NODES - base_node);

    // bbase = sum_{t<k} bucketfill[t]
    {
        int v = (tid < k) ? bucketfill[tid] : 0;  // k <= 195 < 256
#pragma unroll
        for (int off = 32; off; off >>= 1) v += __shfl_down(v, off);
        if ((tid & 63) == 0) red[tid >> 6] = v;
    }
    hist[tid] = 0;
    hist[tid + 256] = 0;
    __syncthreads();
    int bbase = red[0] + red[1] + red[2] + red[3];

    // phase A: node histogram over this bucket's runs
    for (int b = tid; b < NB1; b += 256) {
        int o0 = offs[b * NOFS + k];
        int o1 = offs[b * NOFS + k + 1];
        const unsigned int* reg = staging + (size_t)b * CH;
        for (int i = o0; i < o1; ++i) atomicAdd(&hist[NTL(&reg[i]) >> 17], 1);
    }
    __syncthreads();

    int a = hist[2 * tid], c = hist[2 * tid + 1];
    psum[tid] = a + c;
    __syncthreads();
    for (int off = 1; off < 256; off <<= 1) {
        int v = psum[tid];
        int add = (tid >= off) ? psum[tid - off] : 0;
        __syncthreads();
        psum[tid] = v + add;
        __syncthreads();
    }
    int pex = tid ? psum[tid - 1] : 0;
    {
        int j0 = 2 * tid, j1 = 2 * tid + 1;
        int e0 = bbase + pex;
        int e1 = e0 + a;
        posl[j0] = e0;
        posl[j1] = e1;
        if (j0 < nn) {
            rowptr[base_node + j0] = e0;
            dinv[base_node + j0] = rsqrtf((float)(a + 1));
        }
        if (j1 < nn) {
            rowptr[base_node + j1] = e1;
            dinv[base_node + j1] = rsqrtf((float)(c + 1));
        }
    }
    if (k == NBUCK - 1 && tid == 0) rowptr[N_NODES] = N_EDGES;
    __syncthreads();

    // phase B: placement
    for (int b = tid; b < NB1; b += 256) {
        int o0 = offs[b * NOFS + k];
        int o1 = offs[b * NOFS + k + 1];
        const unsigned int* reg = staging + (size_t)b * CH;
        for (int i = o0; i < o1; ++i) {
            unsigned int pay = NTL(&reg[i]);
            int idx = atomicAdd(&posl[pay >> 17], 1);
            colsrc[idx] = (int)(pay & 0x1FFFFu);
        }
    }
}

// ---------------- GEMM: Hn = (X @ W1) * dinv[row], bf16 out ----------------
__global__ void gemm_k64_n64_kernel(const float* __restrict__ X, const float* __restrict__ W,
                                    const float* __restrict__ dinv,
                                    unsigned short* __restrict__ Hn) {
    __shared__ float Ws[64 * 64];
    __shared__ float Xs[4][64];
    int tid = threadIdx.x;
    {
        const float4* Wv = (const float4*)W;
        float4* Wsv = (float4*)Ws;
#pragma unroll
        for (int i = 0; i < 4; ++i) Wsv[tid + 256 * i] = Wv[tid + 256 * i];
    }
    int row0 = blockIdx.x * 4;
    int r = tid >> 6;
    int col = tid & 63;
    Xs[r][col] = X[(row0 + r) * 64 + col];
    __syncthreads();

    float sum = 0.f;
#pragma unroll
    for (int k = 0; k < 64; ++k) sum += Xs[r][k] * Ws[k * 64 + col];
    Hn[(row0 + r) * 64 + col] = f2bf(sum * dinv[row0 + r]);
}

// ---------------- GEMM layer2: h2n = (h1b @ W2) * dinv[row], bf16 in/out ----------------
__global__ void gemm_k64_n32_bf16_kernel(const unsigned short* __restrict__ Xb,
                                         const float* __restrict__ W,
                                         const float* __restrict__ dinv,
                                         unsigned short* __restrict__ Hn) {
    __shared__ float Ws[64 * 32];
    __shared__ float Xs[8][64];
    int tid = threadIdx.x;
    {
        const float4* Wv = (const float4*)W;
        float4* Wsv = (float4*)Ws;
#pragma unroll
        for (int i = 0; i < 2; ++i) Wsv[tid + 256 * i] = Wv[tid + 256 * i];
    }
    int row0 = blockIdx.x * 8;
    {
        unsigned int w = ((const unsigned int*)(Xb + (size_t)row0 * 64))[tid];
        int r = tid >> 5, p = (tid & 31) << 1;
        Xs[r][p] = bflo(w);
        Xs[r][p + 1] = bfhi(w);
    }
    __syncthreads();

    int r = tid >> 5;
    int col = tid & 31;
    float sum = 0.f;
#pragma unroll
    for (int k = 0; k < 64; ++k) sum += Xs[r][k] * Ws[k * 32 + col];
    Hn[(size_t)(row0 + r) * 32 + col] = f2bf(sum * dinv[row0 + r]);
}

// ---------------- gather64: aggregate + bias + leaky -> bf16 h1b ----------------
__global__ __launch_bounds__(256) void gather64_kernel(
    const unsigned short* __restrict__ Hn, const int* __restrict__ rowptr,
    const int* __restrict__ colsrc, const float* __restrict__ dinv,
    const float* __restrict__ bias, unsigned short* __restrict__ h1b) {
    int wid = (blockIdx.x * blockDim.x + threadIdx.x) >> 6;
    int lane = threadIdx.x & 63;
    if (wid >= N_NODES) return;
    int v = wid;
    int g = lane >> 3;
    int sl = lane & 7;
    int gb = g << 3;
    int beg = rowptr[v], end = rowptr[v + 1];
    int len = end - beg;
    int q = len >> 3, r = len & 7;
    int l0 = beg + g * q + min(g, r);
    int l1 = l0 + q + (g < r ? 1 : 0);

    float acc[8], ac2[8];
#pragma unroll
    for (int i = 0; i < 8; ++i) { acc[i] = 0.f; ac2[i] = 0.f; }
    if (g == 0) {  // self row
        uint4 rw = ((const uint4*)(Hn + (size_t)v * 64))[sl];
        addpack4(acc, rw);
    }
    for (int j0 = l0; j0 < l1; j0 += 8) {
        int myj = j0 + sl;
        int s = (myj < l1) ? NTL(&colsrc[myj]) : 0;
        int cnt = min(8, l1 - j0);
        int t = 0;
        for (; t + 2 <= cnt; t += 2) {
            int s0 = __shfl(s, gb + t);
            int s1 = __shfl(s, gb + t + 1);
            uint4 r0 = ((const uint4*)(Hn + (size_t)s0 * 64))[sl];
            uint4 r1 = ((const uint4*)(Hn + (size_t)s1 * 64))[sl];
            addpack4(acc, r0);
            addpack4(ac2, r1);
        }
        if (t < cnt) {
            int s0 = __shfl(s, gb + t);
            uint4 r0 = ((const uint4*)(Hn + (size_t)s0 * 64))[sl];
            addpack4(acc, r0);
        }
    }
#pragma unroll
    for (int i = 0; i < 8; ++i) {
        acc[i] += ac2[i];
        acc[i] += __shfl_xor(acc[i], 8);
        acc[i] += __shfl_xor(acc[i], 16);
        acc[i] += __shfl_xor(acc[i], 32);
    }
    if (g == 0) {
        float dv = dinv[v];
        float4 b0 = ((const float4*)(bias + sl * 8))[0];
        float4 b1v = ((const float4*)(bias + sl * 8))[1];
        float o[8];
        o[0] = acc[0] * dv + b0.x;  o[1] = acc[1] * dv + b0.y;
        o[2] = acc[2] * dv + b0.z;  o[3] = acc[3] * dv + b0.w;
        o[4] = acc[4] * dv + b1v.x; o[5] = acc[5] * dv + b1v.y;
        o[6] = acc[6] * dv + b1v.z; o[7] = acc[7] * dv + b1v.w;
#pragma unroll
        for (int i = 0; i < 8; ++i) o[i] = o[i] > 0.f ? o[i] : NEG_SLOPE * o[i];
        uint4 pk;
        pk.x = (unsigned int)f2bf(o[0]) | ((unsigned int)f2bf(o[1]) << 16);
        pk.y = (unsigned int)f2bf(o[2]) | ((unsigned int)f2bf(o[3]) << 16);
        pk.z = (unsigned int)f2bf(o[4]) | ((unsigned int)f2bf(o[5]) << 16);
        pk.w = (unsigned int)f2bf(o[6]) | ((unsigned int)f2bf(o[7]) << 16);
        *(uint4*)(h1b + (size_t)v * 64 + sl * 8) = pk;
    }
}

// wave = 8 groups x 8 lanes; lane loads uint2 (8B = 4 dims); bias fused; final out.
__global__ void gather32_kernel(const unsigned short* __restrict__ Hn,
                                const int* __restrict__ rowptr, const int* __restrict__ colsrc,
                                const float* __restrict__ dinv, const float* __restrict__ bias,
                                float* __restrict__ out) {
    int wid = (blockIdx.x * blockDim.x + threadIdx.x) >> 6;
    int lane = threadIdx.x & 63;
    if (wid >= N_NODES) return;
    int v = wid;
    int g = lane >> 3;
    int sl = lane & 7;
    int gb = g << 3;
    int beg = rowptr[v], end = rowptr[v + 1];
    int len = end - beg;
    int q = len >> 3, r = len & 7;
    int l0 = beg + g * q + min(g, r);
    int l1 = l0 + q + (g < r ? 1 : 0);

    float acc[4], ac2[4];
#pragma unroll
    for (int i = 0; i < 4; ++i) { acc[i] = 0.f; ac2[i] = 0.f; }
    if (g == 0) {  // self row
        uint2 rw = ((const uint2*)(Hn + (size_t)v * 32))[sl];
        addpack2(acc, rw);
    }
    for (int j0 = l0; j0 < l1; j0 += 8) {
        int myj = j0 + sl;
        int s = (myj < l1) ? NTL(&colsrc[myj]) : 0;
        int cnt = min(8, l1 - j0);
        int t = 0;
        for (; t + 2 <= cnt; t += 2) {
            int s0 = __shfl(s, gb + t);
            int s1 = __shfl(s, gb + t + 1);
            uint2 r0 = ((const uint2*)(Hn + (size_t)s0 * 32))[sl];
            uint2 r1 = ((const uint2*)(Hn + (size_t)s1 * 32))[sl];
            addpack2(acc, r0);
            addpack2(ac2, r1);
        }
        if (t < cnt) {
            int s0 = __shfl(s, gb + t);
            uint2 r0 = ((const uint2*)(Hn + (size_t)s0 * 32))[sl];
            addpack2(acc, r0);
        }
    }
#pragma unroll
    for (int i = 0; i < 4; ++i) {
        acc[i] += ac2[i];
        acc[i] += __shfl_xor(acc[i], 8);
        acc[i] += __shfl_xor(acc[i], 16);
        acc[i] += __shfl_xor(acc[i], 32);
    }
    if (g == 0) {
        float dv = dinv[v];
        float4 bb = *(const float4*)(bias + sl * 4);
        float o0 = acc[0] * dv + bb.x;
        float o1 = acc[1] * dv + bb.y;
        float o2 = acc[2] * dv + bb.z;
        float o3 = acc[3] * dv + bb.w;
        *(float4*)(out + (size_t)v * 32 + sl * 4) = make_float4(o0, o1, o2, o3);
    }
}

extern "C" void kernel_launch(void* const* d_in, const int* in_sizes, int n_in,
                              void* d_out, int out_size, void* d_ws, size_t ws_size,
                              hipStream_t stream) {
    const float* x = (const float*)d_in[0];
    const int* ei = (const int*)d_in[1];  // [2,E]: src row then dst row
    const float* W1 = (const float*)d_in[2];
    const float* b1 = (const float*)d_in[3];
    const float* W2 = (const float*)d_in[4];
    const float* b2 = (const float*)d_in[5];
    float* out = (float*)d_out;

    const int* src = ei;
    const int* dst = ei + N_EDGES;

    // workspace layout (~46 MB)
    float* dinv = (float*)d_ws;                       // N
    int* rowptr = (int*)(dinv + N_NODES);             // N+1
    int* bucketfill = rowptr + N_NODES + 1;           // NBUCK
    int* offs = bucketfill + NBUCK;                   // NB1*NOFS (313KB)
    int* colsrc = offs + NB1 * NOFS;                  // E
    unsigned short* h1n = (unsigned short*)(colsrc + N_EDGES);              // N*64 bf16 (12.8MB)
    unsigned short* h1b = h1n + (size_t)N_NODES * DIN;                      // N*64 bf16 (12.8MB)
    unsigned short* h2n = h1b + (size_t)N_NODES * DIN;                      // N*32 bf16 (6.4MB)
    unsigned int* staging = (unsigned int*)(h2n + (size_t)N_NODES * DOUT);  // NB1*CH (6.4MB)

    // CSR build (local sort + merge) + norms
    zero_bf_kernel<<<1, 256, 0, stream>>>(bucketfill);
    binpass1_kernel<<<NB1, 256, 0, stream>>>(src, dst, bucketfill, offs, staging);
    binpass2_kernel<<<NBUCK, 256, 0, stream>>>(staging, bucketfill, offs, rowptr, dinv, colsrc);

    // layer 1 GEMM
    gemm_k64_n64_kernel<<<N_NODES / 4, 256, 0, stream>>>(x, W1, dinv, h1n);

    // aggregate layer 1 + bias + leaky -> bf16 h1b
    gather64_kernel<<<(N_NODES * 64 + 255) / 256, 256, 0, stream>>>(
        h1n, rowptr, colsrc, dinv, b1, h1b);

    // layer 2 GEMM (bf16 in/out) with dinv pre-fold
    gemm_k64_n32_bf16_kernel<<<N_NODES / 8, 256, 0, stream>>>(h1b, W2, dinv, h2n);

    // layer 2 aggregation -> final output
    gather32_kernel<<<(N_NODES * 64 + 255) / 256, 256, 0, stream>>>(h2n, rowptr, colsrc, dinv, b2, out);
}

// Round 14
// 249.458 us; speedup vs baseline: 1.0721x; 1.0721x over previous
//
#include <hip/hip_runtime.h>

#define N_NODES 100000
#define N_EDGES 1600000
#define DIN 64
#define DOUT 32
#define NEG_SLOPE 0.01f
#define NBUCK 196          // buckets of 512 nodes (dst >> 9)
#define CH 4096            // edges per binpass1 block
#define NB1 ((N_EDGES + CH - 1) / CH)  // 391
#define NOFS 200           // stride of per-block offs row
#define CAPB 12288         // per-bucket LDS collection capacity (mean 8163, +45 sigma)

__device__ inline unsigned short f2bf(float f) {  // RNE
    unsigned int u = __float_as_uint(f);
    unsigned int r = (u + 0x7fffu + ((u >> 16) & 1u)) >> 16;
    return (unsigned short)r;
}
__device__ inline float bflo(unsigned int p) { return __uint_as_float(p << 16); }
__device__ inline float bfhi(unsigned int p) { return __uint_as_float(p & 0xffff0000u); }
#define NTL(p) __builtin_nontemporal_load(p)

__device__ inline void addpack4(float* a, uint4 r) {
    a[0] += bflo(r.x); a[1] += bfhi(r.x);
    a[2] += bflo(r.y); a[3] += bfhi(r.y);
    a[4] += bflo(r.z); a[5] += bfhi(r.z);
    a[6] += bflo(r.w); a[7] += bfhi(r.w);
}
__device__ inline void addpack2(float* a, uint2 r) {
    a[0] += bflo(r.x); a[1] += bfhi(r.x);
    a[2] += bflo(r.y); a[3] += bfhi(r.y);
}

// ---------------- binning CSR build ----------------
__global__ void zero_bf_kernel(int* __restrict__ bucketfill) {
    if (threadIdx.x < NBUCK) bucketfill[threadIdx.x] = 0;
}

// local counting sort in LDS, then COALESCED copy to the block's dense region.
// Publishes per-block bucket offsets (offs) and global bucket totals (bucketfill).
__global__ __launch_bounds__(256) void binpass1_kernel(const int* __restrict__ src,
                                                       const int* __restrict__ dst,
                                                       int* __restrict__ bucketfill,
                                                       int* __restrict__ offs,
                                                       unsigned int* __restrict__ staging) {
    __shared__ int hist[NBUCK];
    __shared__ int base[NBUCK];
    __shared__ int scanbuf[256];
    __shared__ unsigned int sorted[CH];  // 16KB
    int tid = threadIdx.x;
    int b = blockIdx.x;
    for (int t = tid; t < NBUCK; t += 256) hist[t] = 0;
    __syncthreads();

    int e0 = b * CH + tid;
    int bk[16];
    int rk[16];
    unsigned int pay[16];
#pragma unroll
    for (int i = 0; i < 16; ++i) {
        int e = e0 + i * 256;
        if (e < N_EDGES) {
            int d = NTL(&dst[e]);
            int s = NTL(&src[e]);
            bk[i] = d >> 9;
            pay[i] = (unsigned int)s | ((unsigned int)(d & 511) << 17);
            rk[i] = atomicAdd(&hist[bk[i]], 1);
        } else {
            bk[i] = -1;
        }
    }
    __syncthreads();
    int v = (tid < NBUCK) ? hist[tid] : 0;
    scanbuf[tid] = v;
    __syncthreads();
    for (int off = 1; off < 256; off <<= 1) {
        int a = scanbuf[tid];
        int add = (tid >= off) ? scanbuf[tid - off] : 0;
        __syncthreads();
        scanbuf[tid] = a + add;
        __syncthreads();
    }
    if (tid < NBUCK) {
        int ex = scanbuf[tid] - v;
        base[tid] = ex;
        offs[b * NOFS + tid] = ex;
        if (v) atomicAdd(&bucketfill[tid], v);
    }
    if (tid == 0) offs[b * NOFS + NBUCK] = scanbuf[NBUCK - 1];  // total valid edges in block
    __syncthreads();
    // permutation happens in LDS (banked), not global
#pragma unroll
    for (int i = 0; i < 16; ++i) {
        if (bk[i] >= 0) sorted[base[bk[i]] + rk[i]] = pay[i];
    }
    __syncthreads();
    // linear, fully-coalesced copy out
    uint4* dv = (uint4*)(staging + (size_t)b * CH);
    const uint4* sv = (const uint4*)sorted;
#pragma unroll
    for (int i = 0; i < 4; ++i) dv[tid + 256 * i] = sv[tid + 256 * i];
}

// per-bucket: collect 391 runs into LDS (coalesced run loads), then hist/scan/
// rowptr/dinv/placement from LDS-resident edges.
__global__ __launch_bounds__(256) void binpass2_kernel(const unsigned int* __restrict__ staging,
                                                       const int* __restrict__ bucketfill,
                                                       const int* __restrict__ offs,
                                                       int* __restrict__ rowptr,
                                                       float* __restrict__ dinv,
                                                       int* __restrict__ colsrc) {
    __shared__ unsigned int coll[CAPB];  // 48KB
    __shared__ int lens[NB1 + 1];        // run lengths -> exclusive bases
    __shared__ int starts[NB1];
    __shared__ int hist[512];
    __shared__ int posl[512];
    __shared__ int psum[256];
    __shared__ int red[4];
    int k = blockIdx.x;
    int tid = threadIdx.x;
    int base_node = k << 9;
    int nn = min(512, N_NODES - base_node);

    // bbase = sum_{t<k} bucketfill[t]
    {
        int v = (tid < k) ? bucketfill[tid] : 0;  // k <= 195 < 256
#pragma unroll
        for (int off = 32; off; off >>= 1) v += __shfl_down(v, off);
        if ((tid & 63) == 0) red[tid >> 6] = v;
    }
    hist[tid] = 0;
    hist[tid + 256] = 0;
    for (int bb = tid; bb < NB1; bb += 256) {
        int o0 = offs[bb * NOFS + k];
        int o1 = offs[bb * NOFS + k + 1];
        starts[bb] = o0;
        lens[bb] = o1 - o0;
    }
    __syncthreads();
    int bbase = red[0] + red[1] + red[2] + red[3];

    // exclusive scan of 391 run lengths via 256-thread pair trick
    int a0 = (2 * tid < NB1) ? lens[2 * tid] : 0;
    int a1 = (2 * tid + 1 < NB1) ? lens[2 * tid + 1] : 0;
    psum[tid] = a0 + a1;
    __syncthreads();
    for (int off = 1; off < 256; off <<= 1) {
        int vv = psum[tid];
        int add = (tid >= off) ? psum[tid - off] : 0;
        __syncthreads();
        psum[tid] = vv + add;
        __syncthreads();
    }
    int pex = tid ? psum[tid - 1] : 0;
    if (2 * tid <= NB1) lens[2 * tid] = pex;
    if (2 * tid + 1 <= NB1) lens[2 * tid + 1] = pex + a0;
    __syncthreads();

    // collect runs into coll: wave w handles runs w, w+4, ... (coalesced ~84B loads)
    {
        int wv = tid >> 6, ln = tid & 63;
        for (int bb = wv; bb < NB1; bb += 4) {
            int cb = lens[bb];
            int h = lens[bb + 1] - cb;
            const unsigned int* reg = staging + (size_t)bb * CH + starts[bb];
            for (int i = ln; i < h; i += 64) coll[cb + i] = NTL(&reg[i]);
        }
    }
    __syncthreads();
    int len = lens[NB1];

    // node histogram from LDS
    for (int i = tid; i < len; i += 256) atomicAdd(&hist[coll[i] >> 17], 1);
    __syncthreads();

    // node scan (512 via pair trick)
    int a = hist[2 * tid], c = hist[2 * tid + 1];
    psum[tid] = a + c;
    __syncthreads();
    for (int off = 1; off < 256; off <<= 1) {
        int vv = psum[tid];
        int add = (tid >= off) ? psum[tid - off] : 0;
        __syncthreads();
        psum[tid] = vv + add;
        __syncthreads();
    }
    int pex2 = tid ? psum[tid - 1] : 0;
    {
        int j0 = 2 * tid, j1 = 2 * tid + 1;
        int e0 = bbase + pex2;
        int e1 = e0 + a;
        posl[j0] = e0;
        posl[j1] = e1;
        if (j0 < nn) {
            rowptr[base_node + j0] = e0;
            dinv[base_node + j0] = rsqrtf((float)(a + 1));
        }
        if (j1 < nn) {
            rowptr[base_node + j1] = e1;
            dinv[base_node + j1] = rsqrtf((float)(c + 1));
        }
    }
    if (k == NBUCK - 1 && tid == 0) rowptr[N_NODES] = N_EDGES;
    __syncthreads();

    // placement: scatter within the bucket's L2-local colsrc slice
    for (int i = tid; i < len; i += 256) {
        unsigned int pay = coll[i];
        int idx = atomicAdd(&posl[pay >> 17], 1);
        colsrc[idx] = (int)(pay & 0x1FFFFu);
    }
}

// ---------------- GEMM: Hn = (X @ W1) * dinv[row], bf16 out ----------------
__global__ void gemm_k64_n64_kernel(const float* __restrict__ X, const float* __restrict__ W,
                                    const float* __restrict__ dinv,
                                    unsigned short* __restrict__ Hn) {
    __shared__ float Ws[64 * 64];
    __shared__ float Xs[4][64];
    int tid = threadIdx.x;
    {
        const float4* Wv = (const float4*)W;
        float4* Wsv = (float4*)Ws;
#pragma unroll
        for (int i = 0; i < 4; ++i) Wsv[tid + 256 * i] = Wv[tid + 256 * i];
    }
    int row0 = blockIdx.x * 4;
    int r = tid >> 6;
    int col = tid & 63;
    Xs[r][col] = X[(row0 + r) * 64 + col];
    __syncthreads();

    float sum = 0.f;
#pragma unroll
    for (int k = 0; k < 64; ++k) sum += Xs[r][k] * Ws[k * 64 + col];
    Hn[(row0 + r) * 64 + col] = f2bf(sum * dinv[row0 + r]);
}

// ---------------- GEMM layer2: h2n = (h1b @ W2) * dinv[row], bf16 in/out ----------------
__global__ void gemm_k64_n32_bf16_kernel(const unsigned short* __restrict__ Xb,
                                         const float* __restrict__ W,
                                         const float* __restrict__ dinv,
                                         unsigned short* __restrict__ Hn) {
    __shared__ float Ws[64 * 32];
    __shared__ float Xs[8][64];
    int tid = threadIdx.x;
    {
        const float4* Wv = (const float4*)W;
        float4* Wsv = (float4*)Ws;
#pragma unroll
        for (int i = 0; i < 2; ++i) Wsv[tid + 256 * i] = Wv[tid + 256 * i];
    }
    int row0 = blockIdx.x * 8;
    {
        unsigned int w = ((const unsigned int*)(Xb + (size_t)row0 * 64))[tid];
        int r = tid >> 5, p = (tid & 31) << 1;
        Xs[r][p] = bflo(w);
        Xs[r][p + 1] = bfhi(w);
    }
    __syncthreads();

    int r = tid >> 5;
    int col = tid & 31;
    float sum = 0.f;
#pragma unroll
    for (int k = 0; k < 64; ++k) sum += Xs[r][k] * Ws[k * 32 + col];
    Hn[(size_t)(row0 + r) * 32 + col] = f2bf(sum * dinv[row0 + r]);
}

// ---------------- gather64: aggregate + bias + leaky -> bf16 h1b ----------------
__global__ __launch_bounds__(256) void gather64_kernel(
    const unsigned short* __restrict__ Hn, const int* __restrict__ rowptr,
    const int* __restrict__ colsrc, const float* __restrict__ dinv,
    const float* __restrict__ bias, unsigned short* __restrict__ h1b) {
    int wid = (blockIdx.x * blockDim.x + threadIdx.x) >> 6;
    int lane = threadIdx.x & 63;
    if (wid >= N_NODES) return;
    int v = wid;
    int g = lane >> 3;
    int sl = lane & 7;
    int gb = g << 3;
    int beg = rowptr[v], end = rowptr[v + 1];
    int len = end - beg;
    int q = len >> 3, r = len & 7;
    int l0 = beg + g * q + min(g, r);
    int l1 = l0 + q + (g < r ? 1 : 0);

    float acc[8], ac2[8];
#pragma unroll
    for (int i = 0; i < 8; ++i) { acc[i] = 0.f; ac2[i] = 0.f; }
    if (g == 0) {  // self row
        uint4 rw = ((const uint4*)(Hn + (size_t)v * 64))[sl];
        addpack4(acc, rw);
    }
    for (int j0 = l0; j0 < l1; j0 += 8) {
        int myj = j0 + sl;
        int s = (myj < l1) ? NTL(&colsrc[myj]) : 0;
        int cnt = min(8, l1 - j0);
        int t = 0;
        for (; t + 2 <= cnt; t += 2) {
            int s0 = __shfl(s, gb + t);
            int s1 = __shfl(s, gb + t + 1);
            uint4 r0 = ((const uint4*)(Hn + (size_t)s0 * 64))[sl];
            uint4 r1 = ((const uint4*)(Hn + (size_t)s1 * 64))[sl];
            addpack4(acc, r0);
            addpack4(ac2, r1);
        }
        if (t < cnt) {
            int s0 = __shfl(s, gb + t);
            uint4 r0 = ((const uint4*)(Hn + (size_t)s0 * 64))[sl];
            addpack4(acc, r0);
        }
    }
#pragma unroll
    for (int i = 0; i < 8; ++i) {
        acc[i] += ac2[i];
        acc[i] += __shfl_xor(acc[i], 8);
        acc[i] += __shfl_xor(acc[i], 16);
        acc[i] += __shfl_xor(acc[i], 32);
    }
    if (g == 0) {
        float dv = dinv[v];
        float4 b0 = ((const float4*)(bias + sl * 8))[0];
        float4 b1v = ((const float4*)(bias + sl * 8))[1];
        float o[8];
        o[0] = acc[0] * dv + b0.x;  o[1] = acc[1] * dv + b0.y;
        o[2] = acc[2] * dv + b0.z;  o[3] = acc[3] * dv + b0.w;
        o[4] = acc[4] * dv + b1v.x; o[5] = acc[5] * dv + b1v.y;
        o[6] = acc[6] * dv + b1v.z; o[7] = acc[7] * dv + b1v.w;
#pragma unroll
        for (int i = 0; i < 8; ++i) o[i] = o[i] > 0.f ? o[i] : NEG_SLOPE * o[i];
        uint4 pk;
        pk.x = (unsigned int)f2bf(o[0]) | ((unsigned int)f2bf(o[1]) << 16);
        pk.y = (unsigned int)f2bf(o[2]) | ((unsigned int)f2bf(o[3]) << 16);
        pk.z = (unsigned int)f2bf(o[4]) | ((unsigned int)f2bf(o[5]) << 16);
        pk.w = (unsigned int)f2bf(o[6]) | ((unsigned int)f2bf(o[7]) << 16);
        *(uint4*)(h1b + (size_t)v * 64 + sl * 8) = pk;
    }
}

// wave = 8 groups x 8 lanes; lane loads uint2 (8B = 4 dims); bias fused; final out.
__global__ void gather32_kernel(const unsigned short* __restrict__ Hn,
                                const int* __restrict__ rowptr, const int* __restrict__ colsrc,
                                const float* __restrict__ dinv, const float* __restrict__ bias,
                                float* __restrict__ out) {
    int wid = (blockIdx.x * blockDim.x + threadIdx.x) >> 6;
    int lane = threadIdx.x & 63;
    if (wid >= N_NODES) return;
    int v = wid;
    int g = lane >> 3;
    int sl = lane & 7;
    int gb = g << 3;
    int beg = rowptr[v], end = rowptr[v + 1];
    int len = end - beg;
    int q = len >> 3, r = len & 7;
    int l0 = beg + g * q + min(g, r);
    int l1 = l0 + q + (g < r ? 1 : 0);

    float acc[4], ac2[4];
#pragma unroll
    for (int i = 0; i < 4; ++i) { acc[i] = 0.f; ac2[i] = 0.f; }
    if (g == 0) {  // self row
        uint2 rw = ((const uint2*)(Hn + (size_t)v * 32))[sl];
        addpack2(acc, rw);
    }
    for (int j0 = l0; j0 < l1; j0 += 8) {
        int myj = j0 + sl;
        int s = (myj < l1) ? NTL(&colsrc[myj]) : 0;
        int cnt = min(8, l1 - j0);
        int t = 0;
        for (; t + 2 <= cnt; t += 2) {
            int s0 = __shfl(s, gb + t);
            int s1 = __shfl(s, gb + t + 1);
            uint2 r0 = ((const uint2*)(Hn + (size_t)s0 * 32))[sl];
            uint2 r1 = ((const uint2*)(Hn + (size_t)s1 * 32))[sl];
            addpack2(acc, r0);
            addpack2(ac2, r1);
        }
        if (t < cnt) {
            int s0 = __shfl(s, gb + t);
            uint2 r0 = ((const uint2*)(Hn + (size_t)s0 * 32))[sl];
            addpack2(acc, r0);
        }
    }
#pragma unroll
    for (int i = 0; i < 4; ++i) {
        acc[i] += ac2[i];
        acc[i] += __shfl_xor(acc[i], 8);
        acc[i] += __shfl_xor(acc[i], 16);
        acc[i] += __shfl_xor(acc[i], 32);
    }
    if (g == 0) {
        float dv = dinv[v];
        float4 bb = *(const float4*)(bias + sl * 4);
        float o0 = acc[0] * dv + bb.x;
        float o1 = acc[1] * dv + bb.y;
        float o2 = acc[2] * dv + bb.z;
        float o3 = acc[3] * dv + bb.w;
        *(float4*)(out + (size_t)v * 32 + sl * 4) = make_float4(o0, o1, o2, o3);
    }
}

extern "C" void kernel_launch(void* const* d_in, const int* in_sizes, int n_in,
                              void* d_out, int out_size, void* d_ws, size_t ws_size,
                              hipStream_t stream) {
    const float* x = (const float*)d_in[0];
    const int* ei = (const int*)d_in[1];  // [2,E]: src row then dst row
    const float* W1 = (const float*)d_in[2];
    const float* b1 = (const float*)d_in[3];
    const float* W2 = (const float*)d_in[4];
    const float* b2 = (const float*)d_in[5];
    float* out = (float*)d_out;

    const int* src = ei;
    const int* dst = ei + N_EDGES;

    // workspace layout (~46 MB)
    float* dinv = (float*)d_ws;                       // N
    int* rowptr = (int*)(dinv + N_NODES);             // N+1
    int* bucketfill = rowptr + N_NODES + 1;           // NBUCK
    int* offs = bucketfill + NBUCK;                   // NB1*NOFS
    int* colsrc = offs + NB1 * NOFS;                  // E
    unsigned short* h1n = (unsigned short*)(colsrc + N_EDGES);              // N*64 bf16 (12.8MB)
    unsigned short* h1b = h1n + (size_t)N_NODES * DIN;                      // N*64 bf16 (12.8MB)
    unsigned short* h2n = h1b + (size_t)N_NODES * DIN;                      // N*32 bf16 (6.4MB)
    unsigned int* staging = (unsigned int*)(h2n + (size_t)N_NODES * DOUT);  // NB1*CH (6.4MB)

    // CSR build (LDS-sorted local regions + LDS-collected merge) + norms
    zero_bf_kernel<<<1, 256, 0, stream>>>(bucketfill);
    binpass1_kernel<<<NB1, 256, 0, stream>>>(src, dst, bucketfill, offs, staging);
    binpass2_kernel<<<NBUCK, 256, 0, stream>>>(staging, bucketfill, offs, rowptr, dinv, colsrc);

    // layer 1 GEMM
    gemm_k64_n64_kernel<<<N_NODES / 4, 256, 0, stream>>>(x, W1, dinv, h1n);

    // aggregate layer 1 + bias + leaky -> bf16 h1b
    gather64_kernel<<<(N_NODES * 64 + 255) / 256, 256, 0, stream>>>(
        h1n, rowptr, colsrc, dinv, b1, h1b);

    // layer 2 GEMM (bf16 in/out) with dinv pre-fold
    gemm_k64_n32_bf16_kernel<<<N_NODES / 8, 256, 0, stream>>>(h1b, W2, dinv, h2n);

    // layer 2 aggregation -> final output
    gather32_kernel<<<(N_NODES * 64 + 255) / 256, 256, 0, stream>>>(h2n, rowptr, colsrc, dinv, b2, out);
}

// Round 15
// 218.114 us; speedup vs baseline: 1.2262x; 1.1437x over previous
//
#include <hip/hip_runtime.h>

#define N_NODES 100000
#define N_EDGES 1600000
#define DIN 64
#define DOUT 32
#define NEG_SLOPE 0.01f
#define NBUCK 196          // buckets of 512 nodes (dst >> 9)
#define CH 4096            // edges per binpass1 block
#define NB1 ((N_EDGES + CH - 1) / CH)  // 391
#define NOFS 200           // stride of per-block offs row

__device__ inline unsigned short f2bf(float f) {  // RNE
    unsigned int u = __float_as_uint(f);
    unsigned int r = (u + 0x7fffu + ((u >> 16) & 1u)) >> 16;
    return (unsigned short)r;
}
__device__ inline float bflo(unsigned int p) { return __uint_as_float(p << 16); }
__device__ inline float bfhi(unsigned int p) { return __uint_as_float(p & 0xffff0000u); }
#define NTL(p) __builtin_nontemporal_load(p)

__device__ inline void addpack4(float* a, uint4 r) {
    a[0] += bflo(r.x); a[1] += bfhi(r.x);
    a[2] += bflo(r.y); a[3] += bfhi(r.y);
    a[4] += bflo(r.z); a[5] += bfhi(r.z);
    a[6] += bflo(r.w); a[7] += bfhi(r.w);
}
__device__ inline void addpack2(float* a, uint2 r) {
    a[0] += bflo(r.x); a[1] += bfhi(r.x);
    a[2] += bflo(r.y); a[3] += bfhi(r.y);
}

// ---------------- binning CSR build ----------------
__global__ void zero_bf_kernel(int* __restrict__ bucketfill) {
    if (threadIdx.x < NBUCK) bucketfill[threadIdx.x] = 0;
}

// local counting sort in LDS, then COALESCED copy to the block's dense region.
__global__ __launch_bounds__(256) void binpass1_kernel(const int* __restrict__ src,
                                                       const int* __restrict__ dst,
                                                       int* __restrict__ bucketfill,
                                                       int* __restrict__ offs,
                                                       unsigned int* __restrict__ staging) {
    __shared__ int hist[NBUCK];
    __shared__ int base[NBUCK];
    __shared__ int scanbuf[256];
    __shared__ unsigned int sorted[CH];  // 16KB
    int tid = threadIdx.x;
    int b = blockIdx.x;
    for (int t = tid; t < NBUCK; t += 256) hist[t] = 0;
    __syncthreads();

    int e0 = b * CH + tid;
    int bk[16];
    int rk[16];
    unsigned int pay[16];
#pragma unroll
    for (int i = 0; i < 16; ++i) {
        int e = e0 + i * 256;
        if (e < N_EDGES) {
            int d = NTL(&dst[e]);
            int s = NTL(&src[e]);
            bk[i] = d >> 9;
            pay[i] = (unsigned int)s | ((unsigned int)(d & 511) << 17);
            rk[i] = atomicAdd(&hist[bk[i]], 1);
        } else {
            bk[i] = -1;
        }
    }
    __syncthreads();
    int v = (tid < NBUCK) ? hist[tid] : 0;
    scanbuf[tid] = v;
    __syncthreads();
    for (int off = 1; off < 256; off <<= 1) {
        int a = scanbuf[tid];
        int add = (tid >= off) ? scanbuf[tid - off] : 0;
        __syncthreads();
        scanbuf[tid] = a + add;
        __syncthreads();
    }
    if (tid < NBUCK) {
        int ex = scanbuf[tid] - v;
        base[tid] = ex;
        offs[b * NOFS + tid] = ex;
        if (v) atomicAdd(&bucketfill[tid], v);
    }
    if (tid == 0) offs[b * NOFS + NBUCK] = scanbuf[NBUCK - 1];  // total valid edges
    __syncthreads();
#pragma unroll
    for (int i = 0; i < 16; ++i) {
        if (bk[i] >= 0) sorted[base[bk[i]] + rk[i]] = pay[i];
    }
    __syncthreads();
    uint4* dv = (uint4*)(staging + (size_t)b * CH);
    const uint4* sv = (const uint4*)sorted;
#pragma unroll
    for (int i = 0; i < 4; ++i) dv[tid + 256 * i] = sv[tid + 256 * i];
}

// per-bucket scan over the 391 run lengths -> dstoff[k][b]; also bucketbase[k].
__global__ __launch_bounds__(256) void scank_kernel(const int* __restrict__ offs,
                                                    const int* __restrict__ bucketfill,
                                                    int* __restrict__ dstoff,
                                                    int* __restrict__ bucketbase,
                                                    int* __restrict__ rowptr) {
    __shared__ int lens[512];
    __shared__ int ps[256];
    __shared__ int red[4];
    int k = blockIdx.x;
    int tid = threadIdx.x;
    for (int b = tid; b < 512; b += 256)
        lens[b] = (b < NB1) ? offs[b * NOFS + k + 1] - offs[b * NOFS + k] : 0;
    {
        int v = (tid < k) ? bucketfill[tid] : 0;  // k <= 195 < 256
#pragma unroll
        for (int off = 32; off; off >>= 1) v += __shfl_down(v, off);
        if ((tid & 63) == 0) red[tid >> 6] = v;
    }
    __syncthreads();
    int bb0 = red[0] + red[1] + red[2] + red[3];
    int a0 = lens[2 * tid], a1 = lens[2 * tid + 1];
    ps[tid] = a0 + a1;
    __syncthreads();
    for (int off = 1; off < 256; off <<= 1) {
        int vv = ps[tid];
        int add = (tid >= off) ? ps[tid - off] : 0;
        __syncthreads();
        ps[tid] = vv + add;
        __syncthreads();
    }
    int pex = tid ? ps[tid - 1] : 0;
    if (2 * tid < NB1) dstoff[k * NB1 + 2 * tid] = bb0 + pex;
    if (2 * tid + 1 < NB1) dstoff[k * NB1 + 2 * tid + 1] = bb0 + pex + a0;
    if (tid == 0) bucketbase[k] = bb0;
    if (k == NBUCK - 1 && tid == 0) rowptr[N_NODES] = N_EDGES;
}

// parallel permutation: block b streams its sorted region; each edge binary-searches
// its bucket in LDS offs table; writes to bucket-contiguous staging2 (run-contiguous).
__global__ __launch_bounds__(256) void copyruns_kernel(const unsigned int* __restrict__ staging,
                                                       const int* __restrict__ offs,
                                                       const int* __restrict__ dstoff,
                                                       unsigned int* __restrict__ staging2) {
    __shared__ int offsL[NBUCK + 1];
    __shared__ int dstL[NBUCK];
    int tid = threadIdx.x;
    int b = blockIdx.x;
    for (int t = tid; t <= NBUCK; t += 256) offsL[t] = offs[b * NOFS + t];
    for (int t = tid; t < NBUCK; t += 256) dstL[t] = dstoff[t * NB1 + b];
    __syncthreads();
    int total = offsL[NBUCK];
    const unsigned int* reg = staging + (size_t)b * CH;
#pragma unroll
    for (int j = 0; j < 16; ++j) {
        int i = tid + j * 256;
        if (i < total) {
            unsigned int pay = reg[i];  // coalesced, L2-hot
            int lo = 0, hi = NBUCK;
            while (hi - lo > 1) {
                int mid = (lo + hi) >> 1;
                if (offsL[mid] <= i) lo = mid; else hi = mid;
            }
            staging2[dstL[lo] + (i - offsL[lo])] = pay;
        }
    }
}

// per-bucket finish: CONTIGUOUS slice read (twice, L2-hot), 1024 threads (16 waves).
__global__ __launch_bounds__(1024) void binpass2_kernel(const unsigned int* __restrict__ staging2,
                                                        const int* __restrict__ bucketfill,
                                                        const int* __restrict__ bucketbase,
                                                        int* __restrict__ rowptr,
                                                        float* __restrict__ dinv,
                                                        int* __restrict__ colsrc) {
    __shared__ int hist[512];
    __shared__ int posl[512];
    __shared__ int sh[512];
    int k = blockIdx.x;
    int tid = threadIdx.x;
    int base_node = k << 9;
    int nn = min(512, N_NODES - base_node);
    int base = bucketbase[k];
    int len = bucketfill[k];

    if (tid < 512) hist[tid] = 0;
    __syncthreads();
    for (int i = tid; i < len; i += 1024) atomicAdd(&hist[staging2[base + i] >> 17], 1);
    __syncthreads();

    int v = 0;
    if (tid < 512) { v = hist[tid]; sh[tid] = v; }
    __syncthreads();
    for (int off = 1; off < 512; off <<= 1) {
        int a = 0, add = 0;
        if (tid < 512) { a = sh[tid]; add = (tid >= off) ? sh[tid - off] : 0; }
        __syncthreads();
        if (tid < 512) sh[tid] = a + add;
        __syncthreads();
    }
    if (tid < 512) {
        int excl = sh[tid] - v;
        posl[tid] = base + excl;
        if (tid < nn) {
            rowptr[base_node + tid] = base + excl;
            dinv[base_node + tid] = rsqrtf((float)(v + 1));
        }
    }
    __syncthreads();
    for (int i = tid; i < len; i += 1024) {
        unsigned int pay = staging2[base + i];
        int idx = atomicAdd(&posl[pay >> 17], 1);
        colsrc[idx] = (int)(pay & 0x1FFFFu);
    }
}

// ---------------- GEMM: Hn = (X @ W1) * dinv[row], bf16 out ----------------
__global__ void gemm_k64_n64_kernel(const float* __restrict__ X, const float* __restrict__ W,
                                    const float* __restrict__ dinv,
                                    unsigned short* __restrict__ Hn) {
    __shared__ float Ws[64 * 64];
    __shared__ float Xs[4][64];
    int tid = threadIdx.x;
    {
        const float4* Wv = (const float4*)W;
        float4* Wsv = (float4*)Ws;
#pragma unroll
        for (int i = 0; i < 4; ++i) Wsv[tid + 256 * i] = Wv[tid + 256 * i];
    }
    int row0 = blockIdx.x * 4;
    int r = tid >> 6;
    int col = tid & 63;
    Xs[r][col] = X[(row0 + r) * 64 + col];
    __syncthreads();

    float sum = 0.f;
#pragma unroll
    for (int k = 0; k < 64; ++k) sum += Xs[r][k] * Ws[k * 64 + col];
    Hn[(row0 + r) * 64 + col] = f2bf(sum * dinv[row0 + r]);
}

// ---------------- GEMM layer2: h2n = (h1b @ W2) * dinv[row], bf16 in/out ----------------
__global__ void gemm_k64_n32_bf16_kernel(const unsigned short* __restrict__ Xb,
                                         const float* __restrict__ W,
                                         const float* __restrict__ dinv,
                                         unsigned short* __restrict__ Hn) {
    __shared__ float Ws[64 * 32];
    __shared__ float Xs[8][64];
    int tid = threadIdx.x;
    {
        const float4* Wv = (const float4*)W;
        float4* Wsv = (float4*)Ws;
#pragma unroll
        for (int i = 0; i < 2; ++i) Wsv[tid + 256 * i] = Wv[tid + 256 * i];
    }
    int row0 = blockIdx.x * 8;
    {
        unsigned int w = ((const unsigned int*)(Xb + (size_t)row0 * 64))[tid];
        int r = tid >> 5, p = (tid & 31) << 1;
        Xs[r][p] = bflo(w);
        Xs[r][p + 1] = bfhi(w);
    }
    __syncthreads();

    int r = tid >> 5;
    int col = tid & 31;
    float sum = 0.f;
#pragma unroll
    for (int k = 0; k < 64; ++k) sum += Xs[r][k] * Ws[k * 32 + col];
    Hn[(size_t)(row0 + r) * 32 + col] = f2bf(sum * dinv[row0 + r]);
}

// ---------------- gather64: aggregate + bias + leaky -> bf16 h1b ----------------
__global__ __launch_bounds__(256) void gather64_kernel(
    const unsigned short* __restrict__ Hn, const int* __restrict__ rowptr,
    const int* __restrict__ colsrc, const float* __restrict__ dinv,
    const float* __restrict__ bias, unsigned short* __restrict__ h1b) {
    int wid = (blockIdx.x * blockDim.x + threadIdx.x) >> 6;
    int lane = threadIdx.x & 63;
    if (wid >= N_NODES) return;
    int v = wid;
    int g = lane >> 3;
    int sl = lane & 7;
    int gb = g << 3;
    int beg = rowptr[v], end = rowptr[v + 1];
    int len = end - beg;
    int q = len >> 3, r = len & 7;
    int l0 = beg + g * q + min(g, r);
    int l1 = l0 + q + (g < r ? 1 : 0);

    float acc[8], ac2[8];
#pragma unroll
    for (int i = 0; i < 8; ++i) { acc[i] = 0.f; ac2[i] = 0.f; }
    if (g == 0) {  // self row
        uint4 rw = ((const uint4*)(Hn + (size_t)v * 64))[sl];
        addpack4(acc, rw);
    }
    for (int j0 = l0; j0 < l1; j0 += 8) {
        int myj = j0 + sl;
        int s = (myj < l1) ? NTL(&colsrc[myj]) : 0;
        int cnt = min(8, l1 - j0);
        int t = 0;
        for (; t + 2 <= cnt; t += 2) {
            int s0 = __shfl(s, gb + t);
            int s1 = __shfl(s, gb + t + 1);
            uint4 r0 = ((const uint4*)(Hn + (size_t)s0 * 64))[sl];
            uint4 r1 = ((const uint4*)(Hn + (size_t)s1 * 64))[sl];
            addpack4(acc, r0);
            addpack4(ac2, r1);
        }
        if (t < cnt) {
            int s0 = __shfl(s, gb + t);
            uint4 r0 = ((const uint4*)(Hn + (size_t)s0 * 64))[sl];
            addpack4(acc, r0);
        }
    }
#pragma unroll
    for (int i = 0; i < 8; ++i) {
        acc[i] += ac2[i];
        acc[i] += __shfl_xor(acc[i], 8);
        acc[i] += __shfl_xor(acc[i], 16);
        acc[i] += __shfl_xor(acc[i], 32);
    }
    if (g == 0) {
        float dv = dinv[v];
        float4 b0 = ((const float4*)(bias + sl * 8))[0];
        float4 b1v = ((const float4*)(bias + sl * 8))[1];
        float o[8];
        o[0] = acc[0] * dv + b0.x;  o[1] = acc[1] * dv + b0.y;
        o[2] = acc[2] * dv + b0.z;  o[3] = acc[3] * dv + b0.w;
        o[4] = acc[4] * dv + b1v.x; o[5] = acc[5] * dv + b1v.y;
        o[6] = acc[6] * dv + b1v.z; o[7] = acc[7] * dv + b1v.w;
#pragma unroll
        for (int i = 0; i < 8; ++i) o[i] = o[i] > 0.f ? o[i] : NEG_SLOPE * o[i];
        uint4 pk;
        pk.x = (unsigned int)f2bf(o[0]) | ((unsigned int)f2bf(o[1]) << 16);
        pk.y = (unsigned int)f2bf(o[2]) | ((unsigned int)f2bf(o[3]) << 16);
        pk.z = (unsigned int)f2bf(o[4]) | ((unsigned int)f2bf(o[5]) << 16);
        pk.w = (unsigned int)f2bf(o[6]) | ((unsigned int)f2bf(o[7]) << 16);
        *(uint4*)(h1b + (size_t)v * 64 + sl * 8) = pk;
    }
}

// wave = 8 groups x 8 lanes; lane loads uint2 (8B = 4 dims); bias fused; final out.
__global__ void gather32_kernel(const unsigned short* __restrict__ Hn,
                                const int* __restrict__ rowptr, const int* __restrict__ colsrc,
                                const float* __restrict__ dinv, const float* __restrict__ bias,
                                float* __restrict__ out) {
    int wid = (blockIdx.x * blockDim.x + threadIdx.x) >> 6;
    int lane = threadIdx.x & 63;
    if (wid >= N_NODES) return;
    int v = wid;
    int g = lane >> 3;
    int sl = lane & 7;
    int gb = g << 3;
    int beg = rowptr[v], end = rowptr[v + 1];
    int len = end - beg;
    int q = len >> 3, r = len & 7;
    int l0 = beg + g * q + min(g, r);
    int l1 = l0 + q + (g < r ? 1 : 0);

    float acc[4], ac2[4];
#pragma unroll
    for (int i = 0; i < 4; ++i) { acc[i] = 0.f; ac2[i] = 0.f; }
    if (g == 0) {  // self row
        uint2 rw = ((const uint2*)(Hn + (size_t)v * 32))[sl];
        addpack2(acc, rw);
    }
    for (int j0 = l0; j0 < l1; j0 += 8) {
        int myj = j0 + sl;
        int s = (myj < l1) ? NTL(&colsrc[myj]) : 0;
        int cnt = min(8, l1 - j0);
        int t = 0;
        for (; t + 2 <= cnt; t += 2) {
            int s0 = __shfl(s, gb + t);
            int s1 = __shfl(s, gb + t + 1);
            uint2 r0 = ((const uint2*)(Hn + (size_t)s0 * 32))[sl];
            uint2 r1 = ((const uint2*)(Hn + (size_t)s1 * 32))[sl];
            addpack2(acc, r0);
            addpack2(ac2, r1);
        }
        if (t < cnt) {
            int s0 = __shfl(s, gb + t);
            uint2 r0 = ((const uint2*)(Hn + (size_t)s0 * 32))[sl];
            addpack2(acc, r0);
        }
    }
#pragma unroll
    for (int i = 0; i < 4; ++i) {
        acc[i] += ac2[i];
        acc[i] += __shfl_xor(acc[i], 8);
        acc[i] += __shfl_xor(acc[i], 16);
        acc[i] += __shfl_xor(acc[i], 32);
    }
    if (g == 0) {
        float dv = dinv[v];
        float4 bb = *(const float4*)(bias + sl * 4);
        float o0 = acc[0] * dv + bb.x;
        float o1 = acc[1] * dv + bb.y;
        float o2 = acc[2] * dv + bb.z;
        float o3 = acc[3] * dv + bb.w;
        *(float4*)(out + (size_t)v * 32 + sl * 4) = make_float4(o0, o1, o2, o3);
    }
}

extern "C" void kernel_launch(void* const* d_in, const int* in_sizes, int n_in,
                              void* d_out, int out_size, void* d_ws, size_t ws_size,
                              hipStream_t stream) {
    const float* x = (const float*)d_in[0];
    const int* ei = (const int*)d_in[1];  // [2,E]: src row then dst row
    const float* W1 = (const float*)d_in[2];
    const float* b1 = (const float*)d_in[3];
    const float* W2 = (const float*)d_in[4];
    const float* b2 = (const float*)d_in[5];
    float* out = (float*)d_out;

    const int* src = ei;
    const int* dst = ei + N_EDGES;

    // workspace layout (~53 MB)
    float* dinv = (float*)d_ws;                       // N
    int* rowptr = (int*)(dinv + N_NODES);             // N+1
    int* bucketfill = rowptr + N_NODES + 1;           // NBUCK
    int* bucketbase = bucketfill + NBUCK;             // NBUCK
    int* offs = bucketbase + NBUCK;                   // NB1*NOFS
    int* dstoff = offs + NB1 * NOFS;                  // NBUCK*NB1
    int* colsrc = dstoff + NBUCK * NB1;               // E
    unsigned short* h1n = (unsigned short*)(colsrc + N_EDGES);              // N*64 bf16 (12.8MB)
    unsigned short* h1b = h1n + (size_t)N_NODES * DIN;                      // N*64 bf16 (12.8MB)
    unsigned short* h2n = h1b + (size_t)N_NODES * DIN;                      // N*32 bf16 (6.4MB)
    unsigned int* staging = (unsigned int*)(h2n + (size_t)N_NODES * DOUT);  // NB1*CH (6.4MB)
    unsigned int* staging2 = staging + (size_t)NB1 * CH;                    // E (6.4MB)

    // CSR build: local sort -> per-bucket offsets -> permutation -> finish
    zero_bf_kernel<<<1, 256, 0, stream>>>(bucketfill);
    binpass1_kernel<<<NB1, 256, 0, stream>>>(src, dst, bucketfill, offs, staging);
    scank_kernel<<<NBUCK, 256, 0, stream>>>(offs, bucketfill, dstoff, bucketbase, rowptr);
    copyruns_kernel<<<NB1, 256, 0, stream>>>(staging, offs, dstoff, staging2);
    binpass2_kernel<<<NBUCK, 1024, 0, stream>>>(staging2, bucketfill, bucketbase, rowptr, dinv, colsrc);

    // layer 1 GEMM
    gemm_k64_n64_kernel<<<N_NODES / 4, 256, 0, stream>>>(x, W1, dinv, h1n);

    // aggregate layer 1 + bias + leaky -> bf16 h1b
    gather64_kernel<<<(N_NODES * 64 + 255) / 256, 256, 0, stream>>>(
        h1n, rowptr, colsrc, dinv, b1, h1b);

    // layer 2 GEMM (bf16 in/out) with dinv pre-fold
    gemm_k64_n32_bf16_kernel<<<N_NODES / 8, 256, 0, stream>>>(h1b, W2, dinv, h2n);

    // layer 2 aggregation -> final output
    gather32_kernel<<<(N_NODES * 64 + 255) / 256, 256, 0, stream>>>(h2n, rowptr, colsrc, dinv, b2, out);
}

// Round 16
// 173.971 us; speedup vs baseline: 1.5373x; 1.2537x over previous
//
#include <hip/hip_runtime.h>

#define N_NODES 100000
#define N_EDGES 1600000
#define DIN 64
#define DOUT 32
#define NEG_SLOPE 0.01f
#define NBUCK 196          // buckets of 512 nodes (dst >> 9)
#define CAP 12288          // staging capacity per bucket (mean 8163, ~36 sigma)
#define CH 4096            // edges per binpass1 block
#define NB1 ((N_EDGES + CH - 1) / CH)  // 391

__device__ inline unsigned short f2bf(float f) {  // RNE
    unsigned int u = __float_as_uint(f);
    unsigned int r = (u + 0x7fffu + ((u >> 16) & 1u)) >> 16;
    return (unsigned short)r;
}
__device__ inline float bflo(unsigned int p) { return __uint_as_float(p << 16); }
__device__ inline float bfhi(unsigned int p) { return __uint_as_float(p & 0xffff0000u); }
#define NTL(p) __builtin_nontemporal_load(p)

__device__ inline void addpack4(float* a, uint4 r) {
    a[0] += bflo(r.x); a[1] += bfhi(r.x);
    a[2] += bflo(r.y); a[3] += bfhi(r.y);
    a[4] += bflo(r.z); a[5] += bfhi(r.z);
    a[6] += bflo(r.w); a[7] += bfhi(r.w);
}
__device__ inline void addpack2(float* a, uint2 r) {
    a[0] += bflo(r.x); a[1] += bfhi(r.x);
    a[2] += bflo(r.y); a[3] += bfhi(r.y);
}

// ---------------- binning CSR build ----------------
__global__ void zero_bf_kernel(int* __restrict__ bucketfill) {
    if (threadIdx.x < NBUCK) bucketfill[threadIdx.x] = 0;
}

// LDS counting sort, then per-run global reservation + contiguous run copy into
// the bucket's CAP-strided region. Writes are run-contiguous (dense lines).
__global__ __launch_bounds__(256) void binpass1_kernel(const int* __restrict__ src,
                                                       const int* __restrict__ dst,
                                                       int* __restrict__ bucketfill,
                                                       unsigned int* __restrict__ staging2) {
    __shared__ int hist[NBUCK];
    __shared__ int base[NBUCK];
    __shared__ int gbase[NBUCK];
    __shared__ int scanbuf[256];
    __shared__ unsigned int sorted[CH];  // 16KB
    int tid = threadIdx.x;
    int b = blockIdx.x;
    for (int t = tid; t < NBUCK; t += 256) hist[t] = 0;
    __syncthreads();

    int e0 = b * CH + tid;
    int bk[16];
    int rk[16];
    unsigned int pay[16];
#pragma unroll
    for (int i = 0; i < 16; ++i) {
        int e = e0 + i * 256;
        if (e < N_EDGES) {
            int d = NTL(&dst[e]);
            int s = NTL(&src[e]);
            bk[i] = d >> 9;
            pay[i] = (unsigned int)s | ((unsigned int)(d & 511) << 17);
            rk[i] = atomicAdd(&hist[bk[i]], 1);
        } else {
            bk[i] = -1;
        }
    }
    __syncthreads();
    int v = (tid < NBUCK) ? hist[tid] : 0;
    scanbuf[tid] = v;
    __syncthreads();
    for (int off = 1; off < 256; off <<= 1) {
        int a = scanbuf[tid];
        int add = (tid >= off) ? scanbuf[tid - off] : 0;
        __syncthreads();
        scanbuf[tid] = a + add;
        __syncthreads();
    }
    if (tid < NBUCK) {
        base[tid] = scanbuf[tid] - v;
        gbase[tid] = v ? atomicAdd(&bucketfill[tid], v) : 0;
    }
    __syncthreads();
#pragma unroll
    for (int i = 0; i < 16; ++i) {
        if (bk[i] >= 0) sorted[base[bk[i]] + rk[i]] = pay[i];
    }
    __syncthreads();
    // wave w copies runs w, w+4, ... (each ~21 edges, contiguous in dst)
    int wv = tid >> 6, ln = tid & 63;
    for (int k = wv; k < NBUCK; k += 4) {
        int h = hist[k];
        int b0 = base[k];
        int g0 = gbase[k];
        unsigned int* dp = staging2 + (size_t)k * CAP;
        for (int i = ln; i < h; i += 64)
            if (g0 + i < CAP) dp[g0 + i] = sorted[b0 + i];
    }
}

// per-bucket finish: contiguous slice read (1024 threads), inline bbase prefix,
// node hist -> scan -> rowptr/dinv -> exact CSR placement.
__global__ __launch_bounds__(1024) void binpass2_kernel(const unsigned int* __restrict__ staging2,
                                                        const int* __restrict__ bucketfill,
                                                        int* __restrict__ rowptr,
                                                        float* __restrict__ dinv,
                                                        int* __restrict__ colsrc) {
    __shared__ int hist[512];
    __shared__ int posl[512];
    __shared__ int sh[512];
    __shared__ int red[4];
    int k = blockIdx.x;
    int tid = threadIdx.x;
    int base_node = k << 9;
    int nn = min(512, N_NODES - base_node);
    int len = min(bucketfill[k], CAP);

    if (tid < 256) {
        int v = (tid < k) ? bucketfill[tid] : 0;  // k <= 195 < 256
#pragma unroll
        for (int off = 32; off; off >>= 1) v += __shfl_down(v, off);
        if ((tid & 63) == 0) red[tid >> 6] = v;
    }
    if (tid < 512) hist[tid] = 0;
    __syncthreads();
    int bbase = red[0] + red[1] + red[2] + red[3];
    const unsigned int* stg = staging2 + (size_t)k * CAP;

    for (int i = tid; i < len; i += 1024) atomicAdd(&hist[stg[i] >> 17], 1);
    __syncthreads();

    int v = 0;
    if (tid < 512) { v = hist[tid]; sh[tid] = v; }
    __syncthreads();
    for (int off = 1; off < 512; off <<= 1) {
        int a = 0, add = 0;
        if (tid < 512) { a = sh[tid]; add = (tid >= off) ? sh[tid - off] : 0; }
        __syncthreads();
        if (tid < 512) sh[tid] = a + add;
        __syncthreads();
    }
    if (tid < 512) {
        int excl = sh[tid] - v;
        posl[tid] = bbase + excl;
        if (tid < nn) {
            rowptr[base_node + tid] = bbase + excl;
            dinv[base_node + tid] = rsqrtf((float)(v + 1));
        }
    }
    if (k == NBUCK - 1 && tid == 0) rowptr[N_NODES] = N_EDGES;
    __syncthreads();
    for (int i = tid; i < len; i += 1024) {
        unsigned int pay = stg[i];
        int idx = atomicAdd(&posl[pay >> 17], 1);
        colsrc[idx] = (int)(pay & 0x1FFFFu);
    }
}

// ---------------- GEMM: Hn = (X @ W1) * dinv[row], bf16 out ----------------
__global__ void gemm_k64_n64_kernel(const float* __restrict__ X, const float* __restrict__ W,
                                    const float* __restrict__ dinv,
                                    unsigned short* __restrict__ Hn) {
    __shared__ float Ws[64 * 64];
    __shared__ float Xs[4][64];
    int tid = threadIdx.x;
    {
        const float4* Wv = (const float4*)W;
        float4* Wsv = (float4*)Ws;
#pragma unroll
        for (int i = 0; i < 4; ++i) Wsv[tid + 256 * i] = Wv[tid + 256 * i];
    }
    int row0 = blockIdx.x * 4;
    int r = tid >> 6;
    int col = tid & 63;
    Xs[r][col] = X[(row0 + r) * 64 + col];
    __syncthreads();

    float sum = 0.f;
#pragma unroll
    for (int k = 0; k < 64; ++k) sum += Xs[r][k] * Ws[k * 64 + col];
    Hn[(row0 + r) * 64 + col] = f2bf(sum * dinv[row0 + r]);
}

// ---------------- GEMM layer2: h2n = (h1b @ W2) * dinv[row], bf16 in/out ----------------
__global__ void gemm_k64_n32_bf16_kernel(const unsigned short* __restrict__ Xb,
                                         const float* __restrict__ W,
                                         const float* __restrict__ dinv,
                                         unsigned short* __restrict__ Hn) {
    __shared__ float Ws[64 * 32];
    __shared__ float Xs[8][64];
    int tid = threadIdx.x;
    {
        const float4* Wv = (const float4*)W;
        float4* Wsv = (float4*)Ws;
#pragma unroll
        for (int i = 0; i < 2; ++i) Wsv[tid + 256 * i] = Wv[tid + 256 * i];
    }
    int row0 = blockIdx.x * 8;
    {
        unsigned int w = ((const unsigned int*)(Xb + (size_t)row0 * 64))[tid];
        int r = tid >> 5, p = (tid & 31) << 1;
        Xs[r][p] = bflo(w);
        Xs[r][p + 1] = bfhi(w);
    }
    __syncthreads();

    int r = tid >> 5;
    int col = tid & 31;
    float sum = 0.f;
#pragma unroll
    for (int k = 0; k < 64; ++k) sum += Xs[r][k] * Ws[k * 32 + col];
    Hn[(size_t)(row0 + r) * 32 + col] = f2bf(sum * dinv[row0 + r]);
}

// ---------------- gather64: node-per-group (8 nodes/wave), no cross-group reduce ----------
// group g (8 lanes) owns node v = wid*8+g; lane sl holds dims [sl*8, sl*8+8) via uint4.
__global__ __launch_bounds__(256) void gather64_kernel(
    const unsigned short* __restrict__ Hn, const int* __restrict__ rowptr,
    const int* __restrict__ colsrc, const float* __restrict__ dinv,
    const float* __restrict__ bias, unsigned short* __restrict__ h1b) {
    int gwid = (blockIdx.x * blockDim.x + threadIdx.x) >> 6;
    int lane = threadIdx.x & 63;
    int g = lane >> 3, sl = lane & 7, gb = g << 3;
    int v = gwid * 8 + g;
    if (v >= N_NODES) return;
    int beg = rowptr[v], end = rowptr[v + 1];

    float acc[8], ac2[8];
#pragma unroll
    for (int i = 0; i < 8; ++i) { acc[i] = 0.f; ac2[i] = 0.f; }
    {   // self row
        uint4 rw = ((const uint4*)(Hn + (size_t)v * 64))[sl];
        addpack4(acc, rw);
    }
    for (int t0 = beg; t0 < end; t0 += 8) {
        int sv = (t0 + sl < end) ? colsrc[t0 + sl] : 0;
        int cnt = min(8, end - t0);
        int t = 0;
        for (; t + 2 <= cnt; t += 2) {
            int s0 = __shfl(sv, gb + t);
            int s1 = __shfl(sv, gb + t + 1);
            uint4 r0 = ((const uint4*)(Hn + (size_t)s0 * 64))[sl];
            uint4 r1 = ((const uint4*)(Hn + (size_t)s1 * 64))[sl];
            addpack4(acc, r0);
            addpack4(ac2, r1);
        }
        if (t < cnt) {
            int s0 = __shfl(sv, gb + t);
            uint4 r0 = ((const uint4*)(Hn + (size_t)s0 * 64))[sl];
            addpack4(acc, r0);
        }
    }
    float dv = dinv[v];
    float4 b0 = ((const float4*)(bias + sl * 8))[0];
    float4 b1v = ((const float4*)(bias + sl * 8))[1];
    float o[8];
    o[0] = (acc[0] + ac2[0]) * dv + b0.x;  o[1] = (acc[1] + ac2[1]) * dv + b0.y;
    o[2] = (acc[2] + ac2[2]) * dv + b0.z;  o[3] = (acc[3] + ac2[3]) * dv + b0.w;
    o[4] = (acc[4] + ac2[4]) * dv + b1v.x; o[5] = (acc[5] + ac2[5]) * dv + b1v.y;
    o[6] = (acc[6] + ac2[6]) * dv + b1v.z; o[7] = (acc[7] + ac2[7]) * dv + b1v.w;
#pragma unroll
    for (int i = 0; i < 8; ++i) o[i] = o[i] > 0.f ? o[i] : NEG_SLOPE * o[i];
    uint4 pk;
    pk.x = (unsigned int)f2bf(o[0]) | ((unsigned int)f2bf(o[1]) << 16);
    pk.y = (unsigned int)f2bf(o[2]) | ((unsigned int)f2bf(o[3]) << 16);
    pk.z = (unsigned int)f2bf(o[4]) | ((unsigned int)f2bf(o[5]) << 16);
    pk.w = (unsigned int)f2bf(o[6]) | ((unsigned int)f2bf(o[7]) << 16);
    *(uint4*)(h1b + (size_t)v * 64 + sl * 8) = pk;
}

// ---------------- gather32: node-per-group; lane sl holds dims [sl*4, sl*4+4) ----------
__global__ __launch_bounds__(256) void gather32_kernel(
    const unsigned short* __restrict__ Hn, const int* __restrict__ rowptr,
    const int* __restrict__ colsrc, const float* __restrict__ dinv,
    const float* __restrict__ bias, float* __restrict__ out) {
    int gwid = (blockIdx.x * blockDim.x + threadIdx.x) >> 6;
    int lane = threadIdx.x & 63;
    int g = lane >> 3, sl = lane & 7, gb = g << 3;
    int v = gwid * 8 + g;
    if (v >= N_NODES) return;
    int beg = rowptr[v], end = rowptr[v + 1];

    float acc[4], ac2[4];
#pragma unroll
    for (int i = 0; i < 4; ++i) { acc[i] = 0.f; ac2[i] = 0.f; }
    {   // self row
        uint2 rw = ((const uint2*)(Hn + (size_t)v * 32))[sl];
        addpack2(acc, rw);
    }
    for (int t0 = beg; t0 < end; t0 += 8) {
        int sv = (t0 + sl < end) ? colsrc[t0 + sl] : 0;
        int cnt = min(8, end - t0);
        int t = 0;
        for (; t + 2 <= cnt; t += 2) {
            int s0 = __shfl(sv, gb + t);
            int s1 = __shfl(sv, gb + t + 1);
            uint2 r0 = ((const uint2*)(Hn + (size_t)s0 * 32))[sl];
            uint2 r1 = ((const uint2*)(Hn + (size_t)s1 * 32))[sl];
            addpack2(acc, r0);
            addpack2(ac2, r1);
        }
        if (t < cnt) {
            int s0 = __shfl(sv, gb + t);
            uint2 r0 = ((const uint2*)(Hn + (size_t)s0 * 32))[sl];
            addpack2(acc, r0);
        }
    }
    float dv = dinv[v];
    float4 bb = ((const float4*)bias)[sl];
    float o0 = (acc[0] + ac2[0]) * dv + bb.x;
    float o1 = (acc[1] + ac2[1]) * dv + bb.y;
    float o2 = (acc[2] + ac2[2]) * dv + bb.z;
    float o3 = (acc[3] + ac2[3]) * dv + bb.w;
    *(float4*)(out + (size_t)v * 32 + sl * 4) = make_float4(o0, o1, o2, o3);
}

extern "C" void kernel_launch(void* const* d_in, const int* in_sizes, int n_in,
                              void* d_out, int out_size, void* d_ws, size_t ws_size,
                              hipStream_t stream) {
    const float* x = (const float*)d_in[0];
    const int* ei = (const int*)d_in[1];  // [2,E]: src row then dst row
    const float* W1 = (const float*)d_in[2];
    const float* b1 = (const float*)d_in[3];
    const float* W2 = (const float*)d_in[4];
    const float* b2 = (const float*)d_in[5];
    float* out = (float*)d_out;

    const int* src = ei;
    const int* dst = ei + N_EDGES;

    // workspace layout, each region 256B-aligned (~48 MB)
    char* p = (char*)d_ws;
    auto alloc = [&](size_t bytes) { char* r = p; p += (bytes + 255) & ~(size_t)255; return r; };
    float* dinv = (float*)alloc(N_NODES * 4);
    int* rowptr = (int*)alloc((N_NODES + 1) * 4);
    int* bucketfill = (int*)alloc(NBUCK * 4);
    int* colsrc = (int*)alloc((size_t)N_EDGES * 4);
    unsigned short* h1n = (unsigned short*)alloc((size_t)N_NODES * DIN * 2);
    unsigned short* h1b = (unsigned short*)alloc((size_t)N_NODES * DIN * 2);
    unsigned short* h2n = (unsigned short*)alloc((size_t)N_NODES * DOUT * 2);
    unsigned int* staging2 = (unsigned int*)alloc((size_t)NBUCK * CAP * 4);

    // CSR build: LDS sort + run reservation -> per-bucket finish
    zero_bf_kernel<<<1, 256, 0, stream>>>(bucketfill);
    binpass1_kernel<<<NB1, 256, 0, stream>>>(src, dst, bucketfill, staging2);
    binpass2_kernel<<<NBUCK, 1024, 0, stream>>>(staging2, bucketfill, rowptr, dinv, colsrc);

    // layer 1 GEMM
    gemm_k64_n64_kernel<<<N_NODES / 4, 256, 0, stream>>>(x, W1, dinv, h1n);

    // aggregate layer 1 + bias + leaky -> bf16 h1b  (8 nodes per wave)
    gather64_kernel<<<(N_NODES / 8 * 64) / 256, 256, 0, stream>>>(
        h1n, rowptr, colsrc, dinv, b1, h1b);

    // layer 2 GEMM (bf16 in/out) with dinv pre-fold
    gemm_k64_n32_bf16_kernel<<<N_NODES / 8, 256, 0, stream>>>(h1b, W2, dinv, h2n);

    // layer 2 aggregation -> final output  (8 nodes per wave)
    gather32_kernel<<<(N_NODES / 8 * 64) / 256, 256, 0, stream>>>(
        h2n, rowptr, colsrc, dinv, b2, out);
}

// Round 17
// 147.811 us; speedup vs baseline: 1.8094x; 1.1770x over previous
//
#include <hip/hip_runtime.h>

#define N_NODES 100000
#define N_EDGES 1600000
#define DIN 64
#define DOUT 32
#define NEG_SLOPE 0.01f
#define NBUCK 196          // buckets of 512 nodes (dst >> 9)
#define CAP 12288          // staging capacity per bucket (mean 8163, ~36 sigma)
#define CH 4096            // edges per binpass1 block
#define NB1 ((N_EDGES + CH - 1) / CH)  // 391

__device__ inline unsigned short f2bf(float f) {  // RNE
    unsigned int u = __float_as_uint(f);
    unsigned int r = (u + 0x7fffu + ((u >> 16) & 1u)) >> 16;
    return (unsigned short)r;
}
__device__ inline float bflo(unsigned int p) { return __uint_as_float(p << 16); }
__device__ inline float bfhi(unsigned int p) { return __uint_as_float(p & 0xffff0000u); }
#define NTL(p) __builtin_nontemporal_load(p)

__device__ inline void addpack4(float* a, uint4 r) {
    a[0] += bflo(r.x); a[1] += bfhi(r.x);
    a[2] += bflo(r.y); a[3] += bfhi(r.y);
    a[4] += bflo(r.z); a[5] += bfhi(r.z);
    a[6] += bflo(r.w); a[7] += bfhi(r.w);
}
__device__ inline void addpack2(float* a, uint2 r) {
    a[0] += bflo(r.x); a[1] += bfhi(r.x);
    a[2] += bflo(r.y); a[3] += bfhi(r.y);
}

// ---------------- binning CSR build ----------------
__global__ void zero_bf_kernel(int* __restrict__ bucketfill) {
    if (threadIdx.x < NBUCK) bucketfill[threadIdx.x] = 0;
}

// LDS counting sort, then per-run global reservation + contiguous run copy into
// the bucket's CAP-strided region. Writes are run-contiguous (dense lines).
__global__ __launch_bounds__(256) void binpass1_kernel(const int* __restrict__ src,
                                                       const int* __restrict__ dst,
                                                       int* __restrict__ bucketfill,
                                                       unsigned int* __restrict__ staging2) {
    __shared__ int hist[NBUCK];
    __shared__ int base[NBUCK];
    __shared__ int gbase[NBUCK];
    __shared__ int scanbuf[256];
    __shared__ unsigned int sorted[CH];  // 16KB
    int tid = threadIdx.x;
    int b = blockIdx.x;
    for (int t = tid; t < NBUCK; t += 256) hist[t] = 0;
    __syncthreads();

    int e0 = b * CH + tid;
    int bk[16];
    int rk[16];
    unsigned int pay[16];
#pragma unroll
    for (int i = 0; i < 16; ++i) {
        int e = e0 + i * 256;
        if (e < N_EDGES) {
            int d = NTL(&dst[e]);
            int s = NTL(&src[e]);
            bk[i] = d >> 9;
            pay[i] = (unsigned int)s | ((unsigned int)(d & 511) << 17);
            rk[i] = atomicAdd(&hist[bk[i]], 1);
        } else {
            bk[i] = -1;
        }
    }
    __syncthreads();
    int v = (tid < NBUCK) ? hist[tid] : 0;
    scanbuf[tid] = v;
    __syncthreads();
    for (int off = 1; off < 256; off <<= 1) {
        int a = scanbuf[tid];
        int add = (tid >= off) ? scanbuf[tid - off] : 0;
        __syncthreads();
        scanbuf[tid] = a + add;
        __syncthreads();
    }
    if (tid < NBUCK) {
        base[tid] = scanbuf[tid] - v;
        gbase[tid] = v ? atomicAdd(&bucketfill[tid], v) : 0;
    }
    __syncthreads();
#pragma unroll
    for (int i = 0; i < 16; ++i) {
        if (bk[i] >= 0) sorted[base[bk[i]] + rk[i]] = pay[i];
    }
    __syncthreads();
    // wave w copies runs w, w+4, ... (each ~21 edges, contiguous in dst)
    int wv = tid >> 6, ln = tid & 63;
    for (int k = wv; k < NBUCK; k += 4) {
        int h = hist[k];
        int b0 = base[k];
        int g0 = gbase[k];
        unsigned int* dp = staging2 + (size_t)k * CAP;
        for (int i = ln; i < h; i += 64)
            if (g0 + i < CAP) dp[g0 + i] = sorted[b0 + i];
    }
}

// per-bucket finish: contiguous slice read (1024 threads), inline bbase prefix,
// node hist -> scan -> rowptr/dinv -> exact CSR placement.
__global__ __launch_bounds__(1024) void binpass2_kernel(const unsigned int* __restrict__ staging2,
                                                        const int* __restrict__ bucketfill,
                                                        int* __restrict__ rowptr,
                                                        float* __restrict__ dinv,
                                                        int* __restrict__ colsrc) {
    __shared__ int hist[512];
    __shared__ int posl[512];
    __shared__ int sh[512];
    __shared__ int red[4];
    int k = blockIdx.x;
    int tid = threadIdx.x;
    int base_node = k << 9;
    int nn = min(512, N_NODES - base_node);
    int len = min(bucketfill[k], CAP);

    if (tid < 256) {
        int v = (tid < k) ? bucketfill[tid] : 0;  // k <= 195 < 256
#pragma unroll
        for (int off = 32; off; off >>= 1) v += __shfl_down(v, off);
        if ((tid & 63) == 0) red[tid >> 6] = v;
    }
    if (tid < 512) hist[tid] = 0;
    __syncthreads();
    int bbase = red[0] + red[1] + red[2] + red[3];
    const unsigned int* stg = staging2 + (size_t)k * CAP;

    for (int i = tid; i < len; i += 1024) atomicAdd(&hist[stg[i] >> 17], 1);
    __syncthreads();

    int v = 0;
    if (tid < 512) { v = hist[tid]; sh[tid] = v; }
    __syncthreads();
    for (int off = 1; off < 512; off <<= 1) {
        int a = 0, add = 0;
        if (tid < 512) { a = sh[tid]; add = (tid >= off) ? sh[tid - off] : 0; }
        __syncthreads();
        if (tid < 512) sh[tid] = a + add;
        __syncthreads();
    }
    if (tid < 512) {
        int excl = sh[tid] - v;
        posl[tid] = bbase + excl;
        if (tid < nn) {
            rowptr[base_node + tid] = bbase + excl;
            dinv[base_node + tid] = rsqrtf((float)(v + 1));
        }
    }
    if (k == NBUCK - 1 && tid == 0) rowptr[N_NODES] = N_EDGES;
    __syncthreads();
    for (int i = tid; i < len; i += 1024) {
        unsigned int pay = stg[i];
        int idx = atomicAdd(&posl[pay >> 17], 1);
        colsrc[idx] = (int)(pay & 0x1FFFFu);
    }
}

// ---------------- GEMM: Hn = (X @ W1) * dinv[row], bf16 out ----------------
// 64 rows x 64 cols per block; thread computes a 4x4 register tile:
// per k: 1 ds_read_b128 (W) + 4 broadcast b32 (Xs, pad 65) + 16 FMA.
__global__ __launch_bounds__(256) void gemm_k64_n64_kernel(const float* __restrict__ X,
                                                           const float* __restrict__ W,
                                                           const float* __restrict__ dinv,
                                                           unsigned short* __restrict__ Hn) {
    __shared__ float Ws[64 * 64];
    __shared__ float Xs[64][65];
    int tid = threadIdx.x;
    int row0 = blockIdx.x * 64;
    {
        const float4* Wv = (const float4*)W;
        float4* Wsv = (float4*)Ws;
#pragma unroll
        for (int i = 0; i < 4; ++i) Wsv[tid + 256 * i] = Wv[tid + 256 * i];
    }
#pragma unroll
    for (int i = 0; i < 4; ++i) {
        int s = tid + i * 256;       // float4 slot: row = s>>4, col4 = (s&15)*4
        int r = s >> 4, c = (s & 15) * 4;
        int gr = row0 + r;
        float4 xv = (gr < N_NODES) ? *(const float4*)(X + (size_t)gr * 64 + c)
                                   : make_float4(0.f, 0.f, 0.f, 0.f);
        Xs[r][c] = xv.x; Xs[r][c + 1] = xv.y; Xs[r][c + 2] = xv.z; Xs[r][c + 3] = xv.w;
    }
    __syncthreads();

    int c4 = (tid & 15) * 4;
    int r4 = (tid >> 4) * 4;
    float a0[4] = {}, a1[4] = {}, a2[4] = {}, a3[4] = {};
#pragma unroll 8
    for (int k = 0; k < 64; ++k) {
        float4 w = *(const float4*)&Ws[(k << 6) + c4];
        float x0 = Xs[r4][k], x1 = Xs[r4 + 1][k], x2 = Xs[r4 + 2][k], x3 = Xs[r4 + 3][k];
        a0[0] += x0 * w.x; a0[1] += x0 * w.y; a0[2] += x0 * w.z; a0[3] += x0 * w.w;
        a1[0] += x1 * w.x; a1[1] += x1 * w.y; a1[2] += x1 * w.z; a1[3] += x1 * w.w;
        a2[0] += x2 * w.x; a2[1] += x2 * w.y; a2[2] += x2 * w.z; a2[3] += x2 * w.w;
        a3[0] += x3 * w.x; a3[1] += x3 * w.y; a3[2] += x3 * w.z; a3[3] += x3 * w.w;
    }
    float* accs[4] = {a0, a1, a2, a3};
#pragma unroll
    for (int r = 0; r < 4; ++r) {
        int gr = row0 + r4 + r;
        if (gr < N_NODES) {
            float dv = dinv[gr];
            float* a = accs[r];
            unsigned int lo = (unsigned int)f2bf(a[0] * dv) | ((unsigned int)f2bf(a[1] * dv) << 16);
            unsigned int hi = (unsigned int)f2bf(a[2] * dv) | ((unsigned int)f2bf(a[3] * dv) << 16);
            *(uint2*)(Hn + (size_t)gr * 64 + c4) = make_uint2(lo, hi);
        }
    }
}

// ---------------- GEMM layer2: h2n = (h1b @ W2) * dinv[row], bf16 in/out ----------------
__global__ void gemm_k64_n32_bf16_kernel(const unsigned short* __restrict__ Xb,
                                         const float* __restrict__ W,
                                         const float* __restrict__ dinv,
                                         unsigned short* __restrict__ Hn) {
    __shared__ float Ws[64 * 32];
    __shared__ float Xs[8][64];
    int tid = threadIdx.x;
    {
        const float4* Wv = (const float4*)W;
        float4* Wsv = (float4*)Ws;
#pragma unroll
        for (int i = 0; i < 2; ++i) Wsv[tid + 256 * i] = Wv[tid + 256 * i];
    }
    int row0 = blockIdx.x * 8;
    {
        unsigned int w = ((const unsigned int*)(Xb + (size_t)row0 * 64))[tid];
        int r = tid >> 5, p = (tid & 31) << 1;
        Xs[r][p] = bflo(w);
        Xs[r][p + 1] = bfhi(w);
    }
    __syncthreads();

    int r = tid >> 5;
    int col = tid & 31;
    float sum = 0.f;
#pragma unroll
    for (int k = 0; k < 64; ++k) sum += Xs[r][k] * Ws[k * 32 + col];
    Hn[(size_t)(row0 + r) * 32 + col] = f2bf(sum * dinv[row0 + r]);
}

// ---------------- gather64: node-per-group (8 nodes/wave), no cross-group reduce ----------
__global__ __launch_bounds__(256) void gather64_kernel(
    const unsigned short* __restrict__ Hn, const int* __restrict__ rowptr,
    const int* __restrict__ colsrc, const float* __restrict__ dinv,
    const float* __restrict__ bias, unsigned short* __restrict__ h1b) {
    int gwid = (blockIdx.x * blockDim.x + threadIdx.x) >> 6;
    int lane = threadIdx.x & 63;
    int g = lane >> 3, sl = lane & 7, gb = g << 3;
    int v = gwid * 8 + g;
    if (v >= N_NODES) return;
    int beg = rowptr[v], end = rowptr[v + 1];

    float acc[8], ac2[8];
#pragma unroll
    for (int i = 0; i < 8; ++i) { acc[i] = 0.f; ac2[i] = 0.f; }
    {   // self row
        uint4 rw = ((const uint4*)(Hn + (size_t)v * 64))[sl];
        addpack4(acc, rw);
    }
    for (int t0 = beg; t0 < end; t0 += 8) {
        int sv = (t0 + sl < end) ? colsrc[t0 + sl] : 0;
        int cnt = min(8, end - t0);
        int t = 0;
        for (; t + 2 <= cnt; t += 2) {
            int s0 = __shfl(sv, gb + t);
            int s1 = __shfl(sv, gb + t + 1);
            uint4 r0 = ((const uint4*)(Hn + (size_t)s0 * 64))[sl];
            uint4 r1 = ((const uint4*)(Hn + (size_t)s1 * 64))[sl];
            addpack4(acc, r0);
            addpack4(ac2, r1);
        }
        if (t < cnt) {
            int s0 = __shfl(sv, gb + t);
            uint4 r0 = ((const uint4*)(Hn + (size_t)s0 * 64))[sl];
            addpack4(acc, r0);
        }
    }
    float dv = dinv[v];
    float4 b0 = ((const float4*)(bias + sl * 8))[0];
    float4 b1v = ((const float4*)(bias + sl * 8))[1];
    float o[8];
    o[0] = (acc[0] + ac2[0]) * dv + b0.x;  o[1] = (acc[1] + ac2[1]) * dv + b0.y;
    o[2] = (acc[2] + ac2[2]) * dv + b0.z;  o[3] = (acc[3] + ac2[3]) * dv + b0.w;
    o[4] = (acc[4] + ac2[4]) * dv + b1v.x; o[5] = (acc[5] + ac2[5]) * dv + b1v.y;
    o[6] = (acc[6] + ac2[6]) * dv + b1v.z; o[7] = (acc[7] + ac2[7]) * dv + b1v.w;
#pragma unroll
    for (int i = 0; i < 8; ++i) o[i] = o[i] > 0.f ? o[i] : NEG_SLOPE * o[i];
    uint4 pk;
    pk.x = (unsigned int)f2bf(o[0]) | ((unsigned int)f2bf(o[1]) << 16);
    pk.y = (unsigned int)f2bf(o[2]) | ((unsigned int)f2bf(o[3]) << 16);
    pk.z = (unsigned int)f2bf(o[4]) | ((unsigned int)f2bf(o[5]) << 16);
    pk.w = (unsigned int)f2bf(o[6]) | ((unsigned int)f2bf(o[7]) << 16);
    *(uint4*)(h1b + (size_t)v * 64 + sl * 8) = pk;
}

// ---------------- gather32: node-per-group; lane sl holds dims [sl*4, sl*4+4) ----------
__global__ __launch_bounds__(256) void gather32_kernel(
    const unsigned short* __restrict__ Hn, const int* __restrict__ rowptr,
    const int* __restrict__ colsrc, const float* __restrict__ dinv,
    const float* __restrict__ bias, float* __restrict__ out) {
    int gwid = (blockIdx.x * blockDim.x + threadIdx.x) >> 6;
    int lane = threadIdx.x & 63;
    int g = lane >> 3, sl = lane & 7, gb = g << 3;
    int v = gwid * 8 + g;
    if (v >= N_NODES) return;
    int beg = rowptr[v], end = rowptr[v + 1];

    float acc[4], ac2[4];
#pragma unroll
    for (int i = 0; i < 4; ++i) { acc[i] = 0.f; ac2[i] = 0.f; }
    {   // self row
        uint2 rw = ((const uint2*)(Hn + (size_t)v * 32))[sl];
        addpack2(acc, rw);
    }
    for (int t0 = beg; t0 < end; t0 += 8) {
        int sv = (t0 + sl < end) ? colsrc[t0 + sl] : 0;
        int cnt = min(8, end - t0);
        int t = 0;
        for (; t + 2 <= cnt; t += 2) {
            int s0 = __shfl(sv, gb + t);
            int s1 = __shfl(sv, gb + t + 1);
            uint2 r0 = ((const uint2*)(Hn + (size_t)s0 * 32))[sl];
            uint2 r1 = ((const uint2*)(Hn + (size_t)s1 * 32))[sl];
            addpack2(acc, r0);
            addpack2(ac2, r1);
        }
        if (t < cnt) {
            int s0 = __shfl(sv, gb + t);
            uint2 r0 = ((const uint2*)(Hn + (size_t)s0 * 32))[sl];
            addpack2(acc, r0);
        }
    }
    float dv = dinv[v];
    float4 bb = ((const float4*)bias)[sl];
    float o0 = (acc[0] + ac2[0]) * dv + bb.x;
    float o1 = (acc[1] + ac2[1]) * dv + bb.y;
    float o2 = (acc[2] + ac2[2]) * dv + bb.z;
    float o3 = (acc[3] + ac2[3]) * dv + bb.w;
    *(float4*)(out + (size_t)v * 32 + sl * 4) = make_float4(o0, o1, o2, o3);
}

extern "C" void kernel_launch(void* const* d_in, const int* in_sizes, int n_in,
                              void* d_out, int out_size, void* d_ws, size_t ws_size,
                              hipStream_t stream) {
    const float* x = (const float*)d_in[0];
    const int* ei = (const int*)d_in[1];  // [2,E]: src row then dst row
    const float* W1 = (const float*)d_in[2];
    const float* b1 = (const float*)d_in[3];
    const float* W2 = (const float*)d_in[4];
    const float* b2 = (const float*)d_in[5];
    float* out = (float*)d_out;

    const int* src = ei;
    const int* dst = ei + N_EDGES;

    // workspace layout, each region 256B-aligned (~48 MB)
    char* p = (char*)d_ws;
    auto alloc = [&](size_t bytes) { char* r = p; p += (bytes + 255) & ~(size_t)255; return r; };
    float* dinv = (float*)alloc(N_NODES * 4);
    int* rowptr = (int*)alloc((N_NODES + 1) * 4);
    int* bucketfill = (int*)alloc(NBUCK * 4);
    int* colsrc = (int*)alloc((size_t)N_EDGES * 4);
    unsigned short* h1n = (unsigned short*)alloc((size_t)N_NODES * DIN * 2);
    unsigned short* h1b = (unsigned short*)alloc((size_t)N_NODES * DIN * 2);
    unsigned short* h2n = (unsigned short*)alloc((size_t)N_NODES * DOUT * 2);
    unsigned int* staging2 = (unsigned int*)alloc((size_t)NBUCK * CAP * 4);

    // CSR build: LDS sort + run reservation -> per-bucket finish
    zero_bf_kernel<<<1, 256, 0, stream>>>(bucketfill);
    binpass1_kernel<<<NB1, 256, 0, stream>>>(src, dst, bucketfill, staging2);
    binpass2_kernel<<<NBUCK, 1024, 0, stream>>>(staging2, bucketfill, rowptr, dinv, colsrc);

    // layer 1 GEMM (64 rows/block, 4x4 register tile per thread)
    gemm_k64_n64_kernel<<<(N_NODES + 63) / 64, 256, 0, stream>>>(x, W1, dinv, h1n);

    // aggregate layer 1 + bias + leaky -> bf16 h1b  (8 nodes per wave)
    gather64_kernel<<<(N_NODES / 8 * 64) / 256, 256, 0, stream>>>(
        h1n, rowptr, colsrc, dinv, b1, h1b);

    // layer 2 GEMM (bf16 in/out) with dinv pre-fold
    gemm_k64_n32_bf16_kernel<<<N_NODES / 8, 256, 0, stream>>>(h1b, W2, dinv, h2n);

    // layer 2 aggregation -> final output  (8 nodes per wave)
    gather32_kernel<<<(N_NODES / 8 * 64) / 256, 256, 0, stream>>>(
        h2n, rowptr, colsrc, dinv, b2, out);
}

// Round 18
// 143.949 us; speedup vs baseline: 1.8580x; 1.0268x over previous
//
#include <hip/hip_runtime.h>

#define N_NODES 100000
#define N_EDGES 1600000
#define DIN 64
#define DOUT 32
#define NEG_SLOPE 0.01f
#define NBUCK 196          // buckets of 512 nodes (dst >> 9)
#define CAP 12288          // staging capacity per bucket (mean 8163, ~36 sigma)
#define CH 4096            // edges per binpass1 block
#define NB1 ((N_EDGES + CH - 1) / CH)  // 391

__device__ inline unsigned short f2bf(float f) {  // RNE
    unsigned int u = __float_as_uint(f);
    unsigned int r = (u + 0x7fffu + ((u >> 16) & 1u)) >> 16;
    return (unsigned short)r;
}
__device__ inline float bflo(unsigned int p) { return __uint_as_float(p << 16); }
__device__ inline float bfhi(unsigned int p) { return __uint_as_float(p & 0xffff0000u); }
#define NTL(p) __builtin_nontemporal_load(p)

__device__ inline void addpack4(float* a, uint4 r) {
    a[0] += bflo(r.x); a[1] += bfhi(r.x);
    a[2] += bflo(r.y); a[3] += bfhi(r.y);
    a[4] += bflo(r.z); a[5] += bfhi(r.z);
    a[6] += bflo(r.w); a[7] += bfhi(r.w);
}
__device__ inline void addpack2(float* a, uint2 r) {
    a[0] += bflo(r.x); a[1] += bfhi(r.x);
    a[2] += bflo(r.y); a[3] += bfhi(r.y);
}

// ---------------- binning CSR build ----------------
// LDS counting sort (per-wave histograms to cut ds-atomic chains), then per-run
// global reservation + contiguous run copy into the bucket's CAP-strided region.
__global__ __launch_bounds__(256) void binpass1_kernel(const int* __restrict__ src,
                                                       const int* __restrict__ dst,
                                                       int* __restrict__ bucketfill,
                                                       unsigned int* __restrict__ staging2) {
    __shared__ int histw[4][NBUCK];   // per-wave histograms
    __shared__ int base[NBUCK];       // block-local exclusive base per bucket
    __shared__ int tot[NBUCK];        // block totals
    __shared__ int gbase[NBUCK];
    __shared__ int scanbuf[256];
    __shared__ unsigned int sorted[CH];  // 16KB
    int tid = threadIdx.x;
    int w = tid >> 6;
    int b = blockIdx.x;
    for (int t = tid; t < 4 * NBUCK; t += 256) ((int*)histw)[t] = 0;
    __syncthreads();

    int e0 = b * CH + tid;
    int bk[16];
    int rk[16];
    unsigned int pay[16];
#pragma unroll
    for (int i = 0; i < 16; ++i) {
        int e = e0 + i * 256;
        if (e < N_EDGES) {
            int d = NTL(&dst[e]);
            int s = NTL(&src[e]);
            bk[i] = d >> 9;
            pay[i] = (unsigned int)s | ((unsigned int)(d & 511) << 17);
            rk[i] = atomicAdd(&histw[w][bk[i]], 1);
        } else {
            bk[i] = -1;
        }
    }
    __syncthreads();
    // per-bucket: wave-offsets + total; then block-exclusive scan of totals
    int v = 0;
    if (tid < NBUCK) {
        int h0 = histw[0][tid], h1 = histw[1][tid], h2 = histw[2][tid], h3 = histw[3][tid];
        histw[0][tid] = 0;
        histw[1][tid] = h0;
        histw[2][tid] = h0 + h1;
        histw[3][tid] = h0 + h1 + h2;
        v = h0 + h1 + h2 + h3;
        tot[tid] = v;
    }
    scanbuf[tid] = (tid < NBUCK) ? v : 0;
    __syncthreads();
    for (int off = 1; off < 256; off <<= 1) {
        int a = scanbuf[tid];
        int add = (tid >= off) ? scanbuf[tid - off] : 0;
        __syncthreads();
        scanbuf[tid] = a + add;
        __syncthreads();
    }
    if (tid < NBUCK) {
        base[tid] = scanbuf[tid] - v;
        gbase[tid] = v ? atomicAdd(&bucketfill[tid], v) : 0;
    }
    __syncthreads();
#pragma unroll
    for (int i = 0; i < 16; ++i) {
        if (bk[i] >= 0) sorted[base[bk[i]] + histw[w][bk[i]] + rk[i]] = pay[i];
    }
    __syncthreads();
    // wave wv copies runs wv, wv+4, ... (each ~21 edges, contiguous in dst)
    int wv = tid >> 6, ln = tid & 63;
    for (int k = wv; k < NBUCK; k += 4) {
        int h = tot[k];
        int b0 = base[k];
        int g0 = gbase[k];
        unsigned int* dp = staging2 + (size_t)k * CAP;
        for (int i = ln; i < h; i += 64)
            if (g0 + i < CAP) dp[g0 + i] = sorted[b0 + i];
    }
}

// per-bucket finish: contiguous slice read (1024 threads), inline bbase prefix,
// node hist -> scan -> rowptr/dinv -> exact CSR placement.
__global__ __launch_bounds__(1024) void binpass2_kernel(const unsigned int* __restrict__ staging2,
                                                        const int* __restrict__ bucketfill,
                                                        int* __restrict__ rowptr,
                                                        float* __restrict__ dinv,
                                                        int* __restrict__ colsrc) {
    __shared__ int hist[512];
    __shared__ int posl[512];
    __shared__ int sh[512];
    __shared__ int red[4];
    int k = blockIdx.x;
    int tid = threadIdx.x;
    int base_node = k << 9;
    int nn = min(512, N_NODES - base_node);
    int len = min(bucketfill[k], CAP);

    if (tid < 256) {
        int v = (tid < k) ? bucketfill[tid] : 0;  // k <= 195 < 256
#pragma unroll
        for (int off = 32; off; off >>= 1) v += __shfl_down(v, off);
        if ((tid & 63) == 0) red[tid >> 6] = v;
    }
    if (tid < 512) hist[tid] = 0;
    __syncthreads();
    int bbase = red[0] + red[1] + red[2] + red[3];
    const unsigned int* stg = staging2 + (size_t)k * CAP;

    for (int i = tid; i < len; i += 1024) atomicAdd(&hist[stg[i] >> 17], 1);
    __syncthreads();

    int v = 0;
    if (tid < 512) { v = hist[tid]; sh[tid] = v; }
    __syncthreads();
    for (int off = 1; off < 512; off <<= 1) {
        int a = 0, add = 0;
        if (tid < 512) { a = sh[tid]; add = (tid >= off) ? sh[tid - off] : 0; }
        __syncthreads();
        if (tid < 512) sh[tid] = a + add;
        __syncthreads();
    }
    if (tid < 512) {
        int excl = sh[tid] - v;
        posl[tid] = bbase + excl;
        if (tid < nn) {
            rowptr[base_node + tid] = bbase + excl;
            dinv[base_node + tid] = rsqrtf((float)(v + 1));
        }
    }
    if (k == NBUCK - 1 && tid == 0) rowptr[N_NODES] = N_EDGES;
    __syncthreads();
    for (int i = tid; i < len; i += 1024) {
        unsigned int pay = stg[i];
        int idx = atomicAdd(&posl[pay >> 17], 1);
        colsrc[idx] = (int)(pay & 0x1FFFFu);
    }
}

// ---------------- GEMM: Hn = (X @ W1) * dinv[row], bf16 out ----------------
__global__ __launch_bounds__(256) void gemm_k64_n64_kernel(const float* __restrict__ X,
                                                           const float* __restrict__ W,
                                                           const float* __restrict__ dinv,
                                                           unsigned short* __restrict__ Hn) {
    __shared__ float Ws[64 * 64];
    __shared__ float Xs[64][65];
    int tid = threadIdx.x;
    int row0 = blockIdx.x * 64;
    {
        const float4* Wv = (const float4*)W;
        float4* Wsv = (float4*)Ws;
#pragma unroll
        for (int i = 0; i < 4; ++i) Wsv[tid + 256 * i] = Wv[tid + 256 * i];
    }
#pragma unroll
    for (int i = 0; i < 4; ++i) {
        int s = tid + i * 256;
        int r = s >> 4, c = (s & 15) * 4;
        int gr = row0 + r;
        float4 xv = (gr < N_NODES) ? *(const float4*)(X + (size_t)gr * 64 + c)
                                   : make_float4(0.f, 0.f, 0.f, 0.f);
        Xs[r][c] = xv.x; Xs[r][c + 1] = xv.y; Xs[r][c + 2] = xv.z; Xs[r][c + 3] = xv.w;
    }
    __syncthreads();

    int c4 = (tid & 15) * 4;
    int r4 = (tid >> 4) * 4;
    float a0[4] = {}, a1[4] = {}, a2[4] = {}, a3[4] = {};
#pragma unroll 8
    for (int k = 0; k < 64; ++k) {
        float4 w = *(const float4*)&Ws[(k << 6) + c4];
        float x0 = Xs[r4][k], x1 = Xs[r4 + 1][k], x2 = Xs[r4 + 2][k], x3 = Xs[r4 + 3][k];
        a0[0] += x0 * w.x; a0[1] += x0 * w.y; a0[2] += x0 * w.z; a0[3] += x0 * w.w;
        a1[0] += x1 * w.x; a1[1] += x1 * w.y; a1[2] += x1 * w.z; a1[3] += x1 * w.w;
        a2[0] += x2 * w.x; a2[1] += x2 * w.y; a2[2] += x2 * w.z; a2[3] += x2 * w.w;
        a3[0] += x3 * w.x; a3[1] += x3 * w.y; a3[2] += x3 * w.z; a3[3] += x3 * w.w;
    }
    float* accs[4] = {a0, a1, a2, a3};
#pragma unroll
    for (int r = 0; r < 4; ++r) {
        int gr = row0 + r4 + r;
        if (gr < N_NODES) {
            float dv = dinv[gr];
            float* a = accs[r];
            unsigned int lo = (unsigned int)f2bf(a[0] * dv) | ((unsigned int)f2bf(a[1] * dv) << 16);
            unsigned int hi = (unsigned int)f2bf(a[2] * dv) | ((unsigned int)f2bf(a[3] * dv) << 16);
            *(uint2*)(Hn + (size_t)gr * 64 + c4) = make_uint2(lo, hi);
        }
    }
}

// ---------------- GEMM layer2: h2n = (h1b @ W2) * dinv[row], bf16 in/out ----------------
__global__ void gemm_k64_n32_bf16_kernel(const unsigned short* __restrict__ Xb,
                                         const float* __restrict__ W,
                                         const float* __restrict__ dinv,
                                         unsigned short* __restrict__ Hn) {
    __shared__ float Ws[64 * 32];
    __shared__ float Xs[8][64];
    int tid = threadIdx.x;
    {
        const float4* Wv = (const float4*)W;
        float4* Wsv = (float4*)Ws;
#pragma unroll
        for (int i = 0; i < 2; ++i) Wsv[tid + 256 * i] = Wv[tid + 256 * i];
    }
    int row0 = blockIdx.x * 8;
    {
        unsigned int w = ((const unsigned int*)(Xb + (size_t)row0 * 64))[tid];
        int r = tid >> 5, p = (tid & 31) << 1;
        Xs[r][p] = bflo(w);
        Xs[r][p + 1] = bfhi(w);
    }
    __syncthreads();

    int r = tid >> 5;
    int col = tid & 31;
    float sum = 0.f;
#pragma unroll
    for (int k = 0; k < 64; ++k) sum += Xs[r][k] * Ws[k * 32 + col];
    Hn[(size_t)(row0 + r) * 32 + col] = f2bf(sum * dinv[row0 + r]);
}

// ---------------- gather64: node-per-group, 8-deep load batching ----------------
__global__ __launch_bounds__(256) void gather64_kernel(
    const unsigned short* __restrict__ Hn, const int* __restrict__ rowptr,
    const int* __restrict__ colsrc, const float* __restrict__ dinv,
    const float* __restrict__ bias, unsigned short* __restrict__ h1b) {
    int gwid = (blockIdx.x * blockDim.x + threadIdx.x) >> 6;
    int lane = threadIdx.x & 63;
    int g = lane >> 3, sl = lane & 7, gb = g << 3;
    int v = gwid * 8 + g;
    if (v >= N_NODES) return;
    int beg = rowptr[v], end = rowptr[v + 1];

    float acc[8], ac2[8];
#pragma unroll
    for (int i = 0; i < 8; ++i) { acc[i] = 0.f; ac2[i] = 0.f; }
    {   // self row
        uint4 rw = ((const uint4*)(Hn + (size_t)v * 64))[sl];
        addpack4(acc, rw);
    }
    int t0 = beg;
    // full chunks: issue all 8 row loads before accumulating (8 in flight)
    for (; t0 + 8 <= end; t0 += 8) {
        int sv = colsrc[t0 + sl];
        uint4 r[8];
#pragma unroll
        for (int t = 0; t < 8; ++t) {
            int s = __shfl(sv, gb + t);
            r[t] = ((const uint4*)(Hn + (size_t)s * 64))[sl];
        }
#pragma unroll
        for (int t = 0; t < 8; t += 2) {
            addpack4(acc, r[t]);
            addpack4(ac2, r[t + 1]);
        }
    }
    // tail
    if (t0 < end) {
        int sv = (t0 + sl < end) ? colsrc[t0 + sl] : 0;
        int cnt = end - t0;
        int t = 0;
        for (; t + 2 <= cnt; t += 2) {
            int s0 = __shfl(sv, gb + t);
            int s1 = __shfl(sv, gb + t + 1);
            uint4 r0 = ((const uint4*)(Hn + (size_t)s0 * 64))[sl];
            uint4 r1 = ((const uint4*)(Hn + (size_t)s1 * 64))[sl];
            addpack4(acc, r0);
            addpack4(ac2, r1);
        }
        if (t < cnt) {
            int s0 = __shfl(sv, gb + t);
            uint4 r0 = ((const uint4*)(Hn + (size_t)s0 * 64))[sl];
            addpack4(acc, r0);
        }
    }
    float dv = dinv[v];
    float4 b0 = ((const float4*)(bias + sl * 8))[0];
    float4 b1v = ((const float4*)(bias + sl * 8))[1];
    float o[8];
    o[0] = (acc[0] + ac2[0]) * dv + b0.x;  o[1] = (acc[1] + ac2[1]) * dv + b0.y;
    o[2] = (acc[2] + ac2[2]) * dv + b0.z;  o[3] = (acc[3] + ac2[3]) * dv + b0.w;
    o[4] = (acc[4] + ac2[4]) * dv + b1v.x; o[5] = (acc[5] + ac2[5]) * dv + b1v.y;
    o[6] = (acc[6] + ac2[6]) * dv + b1v.z; o[7] = (acc[7] + ac2[7]) * dv + b1v.w;
#pragma unroll
    for (int i = 0; i < 8; ++i) o[i] = o[i] > 0.f ? o[i] : NEG_SLOPE * o[i];
    uint4 pk;
    pk.x = (unsigned int)f2bf(o[0]) | ((unsigned int)f2bf(o[1]) << 16);
    pk.y = (unsigned int)f2bf(o[2]) | ((unsigned int)f2bf(o[3]) << 16);
    pk.z = (unsigned int)f2bf(o[4]) | ((unsigned int)f2bf(o[5]) << 16);
    pk.w = (unsigned int)f2bf(o[6]) | ((unsigned int)f2bf(o[7]) << 16);
    *(uint4*)(h1b + (size_t)v * 64 + sl * 8) = pk;
}

// ---------------- gather32: node-per-group, 8-deep load batching ----------------
__global__ __launch_bounds__(256) void gather32_kernel(
    const unsigned short* __restrict__ Hn, const int* __restrict__ rowptr,
    const int* __restrict__ colsrc, const float* __restrict__ dinv,
    const float* __restrict__ bias, float* __restrict__ out) {
    int gwid = (blockIdx.x * blockDim.x + threadIdx.x) >> 6;
    int lane = threadIdx.x & 63;
    int g = lane >> 3, sl = lane & 7, gb = g << 3;
    int v = gwid * 8 + g;
    if (v >= N_NODES) return;
    int beg = rowptr[v], end = rowptr[v + 1];

    float acc[4], ac2[4];
#pragma unroll
    for (int i = 0; i < 4; ++i) { acc[i] = 0.f; ac2[i] = 0.f; }
    {   // self row
        uint2 rw = ((const uint2*)(Hn + (size_t)v * 32))[sl];
        addpack2(acc, rw);
    }
    int t0 = beg;
    for (; t0 + 8 <= end; t0 += 8) {
        int sv = colsrc[t0 + sl];
        uint2 r[8];
#pragma unroll
        for (int t = 0; t < 8; ++t) {
            int s = __shfl(sv, gb + t);
            r[t] = ((const uint2*)(Hn + (size_t)s * 32))[sl];
        }
#pragma unroll
        for (int t = 0; t < 8; t += 2) {
            addpack2(acc, r[t]);
            addpack2(ac2, r[t + 1]);
        }
    }
    if (t0 < end) {
        int sv = (t0 + sl < end) ? colsrc[t0 + sl] : 0;
        int cnt = end - t0;
        int t = 0;
        for (; t + 2 <= cnt; t += 2) {
            int s0 = __shfl(sv, gb + t);
            int s1 = __shfl(sv, gb + t + 1);
            uint2 r0 = ((const uint2*)(Hn + (size_t)s0 * 32))[sl];
            uint2 r1 = ((const uint2*)(Hn + (size_t)s1 * 32))[sl];
            addpack2(acc, r0);
            addpack2(ac2, r1);
        }
        if (t < cnt) {
            int s0 = __shfl(sv, gb + t);
            uint2 r0 = ((const uint2*)(Hn + (size_t)s0 * 32))[sl];
            addpack2(acc, r0);
        }
    }
    float dv = dinv[v];
    float4 bb = ((const float4*)bias)[sl];
    float o0 = (acc[0] + ac2[0]) * dv + bb.x;
    float o1 = (acc[1] + ac2[1]) * dv + bb.y;
    float o2 = (acc[2] + ac2[2]) * dv + bb.z;
    float o3 = (acc[3] + ac2[3]) * dv + bb.w;
    *(float4*)(out + (size_t)v * 32 + sl * 4) = make_float4(o0, o1, o2, o3);
}

extern "C" void kernel_launch(void* const* d_in, const int* in_sizes, int n_in,
                              void* d_out, int out_size, void* d_ws, size_t ws_size,
                              hipStream_t stream) {
    const float* x = (const float*)d_in[0];
    const int* ei = (const int*)d_in[1];  // [2,E]: src row then dst row
    const float* W1 = (const float*)d_in[2];
    const float* b1 = (const float*)d_in[3];
    const float* W2 = (const float*)d_in[4];
    const float* b2 = (const float*)d_in[5];
    float* out = (float*)d_out;

    const int* src = ei;
    const int* dst = ei + N_EDGES;

    // workspace layout, each region 256B-aligned (~48 MB)
    char* p = (char*)d_ws;
    auto alloc = [&](size_t bytes) { char* r = p; p += (bytes + 255) & ~(size_t)255; return r; };
    float* dinv = (float*)alloc(N_NODES * 4);
    int* rowptr = (int*)alloc((N_NODES + 1) * 4);
    int* bucketfill = (int*)alloc(NBUCK * 4);
    int* colsrc = (int*)alloc((size_t)N_EDGES * 4);
    unsigned short* h1n = (unsigned short*)alloc((size_t)N_NODES * DIN * 2);
    unsigned short* h1b = (unsigned short*)alloc((size_t)N_NODES * DIN * 2);
    unsigned short* h2n = (unsigned short*)alloc((size_t)N_NODES * DOUT * 2);
    unsigned int* staging2 = (unsigned int*)alloc((size_t)NBUCK * CAP * 4);

    // CSR build: LDS sort + run reservation -> per-bucket finish
    hipMemsetAsync(bucketfill, 0, NBUCK * sizeof(int), stream);
    binpass1_kernel<<<NB1, 256, 0, stream>>>(src, dst, bucketfill, staging2);
    binpass2_kernel<<<NBUCK, 1024, 0, stream>>>(staging2, bucketfill, rowptr, dinv, colsrc);

    // layer 1 GEMM (64 rows/block, 4x4 register tile per thread)
    gemm_k64_n64_kernel<<<(N_NODES + 63) / 64, 256, 0, stream>>>(x, W1, dinv, h1n);

    // aggregate layer 1 + bias + leaky -> bf16 h1b  (8 nodes per wave)
    gather64_kernel<<<(N_NODES / 8 * 64) / 256, 256, 0, stream>>>(
        h1n, rowptr, colsrc, dinv, b1, h1b);

    // layer 2 GEMM (bf16 in/out) with dinv pre-fold
    gemm_k64_n32_bf16_kernel<<<N_NODES / 8, 256, 0, stream>>>(h1b, W2, dinv, h2n);

    // layer 2 aggregation -> final output  (8 nodes per wave)
    gather32_kernel<<<(N_NODES / 8 * 64) / 256, 256, 0, stream>>>(
        h2n, rowptr, colsrc, dinv, b2, out);
}

// Round 19
// 128.685 us; speedup vs baseline: 2.0783x; 1.1186x over previous
//
#include <hip/hip_runtime.h>

#define N_NODES 100000
#define N_EDGES 1600000
#define DIN 64
#define DOUT 32
#define NEG_SLOPE 0.01f
#define NBUCK 196          // buckets of 512 nodes (dst >> 9)
#define CAP 12288          // capacity per bucket (mean 8163, ~36 sigma)
#define CH 4096            // edges per binpass1 block
#define NB1 ((N_EDGES + CH - 1) / CH)  // 391

__device__ inline unsigned short f2bf(float f) {  // RNE
    unsigned int u = __float_as_uint(f);
    unsigned int r = (u + 0x7fffu + ((u >> 16) & 1u)) >> 16;
    return (unsigned short)r;
}
__device__ inline float bflo(unsigned int p) { return __uint_as_float(p << 16); }
__device__ inline float bfhi(unsigned int p) { return __uint_as_float(p & 0xffff0000u); }
#define NTL(p) __builtin_nontemporal_load(p)

__device__ inline void addpack4(float* a, uint4 r) {
    a[0] += bflo(r.x); a[1] += bfhi(r.x);
    a[2] += bflo(r.y); a[3] += bfhi(r.y);
    a[4] += bflo(r.z); a[5] += bfhi(r.z);
    a[6] += bflo(r.w); a[7] += bfhi(r.w);
}
__device__ inline void addpack2(float* a, uint2 r) {
    a[0] += bflo(r.x); a[1] += bfhi(r.x);
    a[2] += bflo(r.y); a[3] += bfhi(r.y);
}

// ---------------- binning CSR build ----------------
__global__ __launch_bounds__(256) void binpass1_kernel(const int* __restrict__ src,
                                                       const int* __restrict__ dst,
                                                       int* __restrict__ bucketfill,
                                                       unsigned int* __restrict__ staging2) {
    __shared__ int histw[4][NBUCK];   // per-wave histograms
    __shared__ int base[NBUCK];
    __shared__ int tot[NBUCK];
    __shared__ int gbase[NBUCK];
    __shared__ int scanbuf[256];
    __shared__ unsigned int sorted[CH];  // 16KB
    int tid = threadIdx.x;
    int w = tid >> 6;
    int b = blockIdx.x;
    for (int t = tid; t < 4 * NBUCK; t += 256) ((int*)histw)[t] = 0;
    __syncthreads();

    int e0 = b * CH + tid;
    int bk[16];
    int rk[16];
    unsigned int pay[16];
#pragma unroll
    for (int i = 0; i < 16; ++i) {
        int e = e0 + i * 256;
        if (e < N_EDGES) {
            int d = NTL(&dst[e]);
            int s = NTL(&src[e]);
            bk[i] = d >> 9;
            pay[i] = (unsigned int)s | ((unsigned int)(d & 511) << 17);
            rk[i] = atomicAdd(&histw[w][bk[i]], 1);
        } else {
            bk[i] = -1;
        }
    }
    __syncthreads();
    int v = 0;
    if (tid < NBUCK) {
        int h0 = histw[0][tid], h1 = histw[1][tid], h2 = histw[2][tid], h3 = histw[3][tid];
        histw[0][tid] = 0;
        histw[1][tid] = h0;
        histw[2][tid] = h0 + h1;
        histw[3][tid] = h0 + h1 + h2;
        v = h0 + h1 + h2 + h3;
        tot[tid] = v;
    }
    scanbuf[tid] = (tid < NBUCK) ? v : 0;
    __syncthreads();
    for (int off = 1; off < 256; off <<= 1) {
        int a = scanbuf[tid];
        int add = (tid >= off) ? scanbuf[tid - off] : 0;
        __syncthreads();
        scanbuf[tid] = a + add;
        __syncthreads();
    }
    if (tid < NBUCK) {
        base[tid] = scanbuf[tid] - v;
        gbase[tid] = v ? atomicAdd(&bucketfill[tid], v) : 0;
    }
    __syncthreads();
#pragma unroll
    for (int i = 0; i < 16; ++i) {
        if (bk[i] >= 0) sorted[base[bk[i]] + histw[w][bk[i]] + rk[i]] = pay[i];
    }
    __syncthreads();
    int wv = tid >> 6, ln = tid & 63;
    for (int k = wv; k < NBUCK; k += 4) {
        int h = tot[k];
        int b0 = base[k];
        int g0 = gbase[k];
        unsigned int* dp = staging2 + (size_t)k * CAP;
        for (int i = ln; i < h; i += 64)
            if (g0 + i < CAP) dp[g0 + i] = sorted[b0 + i];
    }
}

// per-bucket finish: copy slice to LDS once, then hist/scan/rowptr/dinv/placement.
__global__ __launch_bounds__(1024) void binpass2_kernel(const unsigned int* __restrict__ staging2,
                                                        const int* __restrict__ bucketfill,
                                                        int* __restrict__ rowptr,
                                                        float* __restrict__ dinv,
                                                        int* __restrict__ colsrc) {
    __shared__ unsigned int coll[CAP];  // 48KB
    __shared__ int hist[512];
    __shared__ int posl[512];
    __shared__ int sh[512];
    __shared__ int red[4];
    int k = blockIdx.x;
    int tid = threadIdx.x;
    int base_node = k << 9;
    int nn = min(512, N_NODES - base_node);
    int len = min(bucketfill[k], CAP);

    if (tid < 256) {
        int v = (tid < k) ? bucketfill[tid] : 0;  // k <= 195 < 256
#pragma unroll
        for (int off = 32; off; off >>= 1) v += __shfl_down(v, off);
        if ((tid & 63) == 0) red[tid >> 6] = v;
    }
    if (tid < 512) hist[tid] = 0;
    __syncthreads();
    int bbase = red[0] + red[1] + red[2] + red[3];
    const unsigned int* stg = staging2 + (size_t)k * CAP;

    for (int i = tid; i < len; i += 1024) coll[i] = NTL(&stg[i]);
    __syncthreads();
    for (int i = tid; i < len; i += 1024) atomicAdd(&hist[coll[i] >> 17], 1);
    __syncthreads();

    int v = 0;
    if (tid < 512) { v = hist[tid]; sh[tid] = v; }
    __syncthreads();
    for (int off = 1; off < 512; off <<= 1) {
        int a = 0, add = 0;
        if (tid < 512) { a = sh[tid]; add = (tid >= off) ? sh[tid - off] : 0; }
        __syncthreads();
        if (tid < 512) sh[tid] = a + add;
        __syncthreads();
    }
    if (tid < 512) {
        int excl = sh[tid] - v;
        posl[tid] = bbase + excl;
        if (tid < nn) {
            rowptr[base_node + tid] = bbase + excl;
            dinv[base_node + tid] = rsqrtf((float)(v + 1));
        }
    }
    if (k == NBUCK - 1 && tid == 0) rowptr[N_NODES] = N_EDGES;
    __syncthreads();
    for (int i = tid; i < len; i += 1024) {
        unsigned int pay = coll[i];
        int idx = atomicAdd(&posl[pay >> 17], 1);
        colsrc[idx] = (int)(pay & 0x1FFFFu);
    }
}

// ---------------- GEMM: Hn = (X @ W1) * dinv[row], bf16 out ----------------
__global__ __launch_bounds__(256) void gemm_k64_n64_kernel(const float* __restrict__ X,
                                                           const float* __restrict__ W,
                                                           const float* __restrict__ dinv,
                                                           unsigned short* __restrict__ Hn) {
    __shared__ float Ws[64 * 64];
    __shared__ float Xs[64][65];
    int tid = threadIdx.x;
    int row0 = blockIdx.x * 64;
    {
        const float4* Wv = (const float4*)W;
        float4* Wsv = (float4*)Ws;
#pragma unroll
        for (int i = 0; i < 4; ++i) Wsv[tid + 256 * i] = Wv[tid + 256 * i];
    }
#pragma unroll
    for (int i = 0; i < 4; ++i) {
        int s = tid + i * 256;
        int r = s >> 4, c = (s & 15) * 4;
        int gr = row0 + r;
        float4 xv = (gr < N_NODES) ? *(const float4*)(X + (size_t)gr * 64 + c)
                                   : make_float4(0.f, 0.f, 0.f, 0.f);
        Xs[r][c] = xv.x; Xs[r][c + 1] = xv.y; Xs[r][c + 2] = xv.z; Xs[r][c + 3] = xv.w;
    }
    __syncthreads();

    int c4 = (tid & 15) * 4;
    int r4 = (tid >> 4) * 4;
    float a0[4] = {}, a1[4] = {}, a2[4] = {}, a3[4] = {};
#pragma unroll 8
    for (int k = 0; k < 64; ++k) {
        float4 w = *(const float4*)&Ws[(k << 6) + c4];
        float x0 = Xs[r4][k], x1 = Xs[r4 + 1][k], x2 = Xs[r4 + 2][k], x3 = Xs[r4 + 3][k];
        a0[0] += x0 * w.x; a0[1] += x0 * w.y; a0[2] += x0 * w.z; a0[3] += x0 * w.w;
        a1[0] += x1 * w.x; a1[1] += x1 * w.y; a1[2] += x1 * w.z; a1[3] += x1 * w.w;
        a2[0] += x2 * w.x; a2[1] += x2 * w.y; a2[2] += x2 * w.z; a2[3] += x2 * w.w;
        a3[0] += x3 * w.x; a3[1] += x3 * w.y; a3[2] += x3 * w.z; a3[3] += x3 * w.w;
    }
    float* accs[4] = {a0, a1, a2, a3};
#pragma unroll
    for (int r = 0; r < 4; ++r) {
        int gr = row0 + r4 + r;
        if (gr < N_NODES) {
            float dv = dinv[gr];
            float* a = accs[r];
            unsigned int lo = (unsigned int)f2bf(a[0] * dv) | ((unsigned int)f2bf(a[1] * dv) << 16);
            unsigned int hi = (unsigned int)f2bf(a[2] * dv) | ((unsigned int)f2bf(a[3] * dv) << 16);
            *(uint2*)(Hn + (size_t)gr * 64 + c4) = make_uint2(lo, hi);
        }
    }
}

// ---------------- fused gather64 + bias/leaky + (R @ W2)*dinv -> h2n ----------------
// Block owns 32 nodes (4 waves x 8 groups). Gather phase identical to r18's
// gather64 but results go to LDS R[32][65]; then the block computes the 32x32
// W2 tile (thread = 1 row x 4 cols) and writes bf16 h2n. No h1b round-trip.
__global__ __launch_bounds__(256) void gather64_fused_kernel(
    const unsigned short* __restrict__ Hn, const int* __restrict__ rowptr,
    const int* __restrict__ colsrc, const float* __restrict__ dinv,
    const float* __restrict__ bias, const float* __restrict__ W2,
    unsigned short* __restrict__ h2n) {
    __shared__ float R[32][65];    // staged post-activation rows (8.3KB)
    __shared__ float W2s[64][32];  // 8KB, float4-readable
    int tid = threadIdx.x;
    {
        const float4* Wv = (const float4*)W2;
        float4* Wsv = (float4*)W2s;
#pragma unroll
        for (int i = 0; i < 2; ++i) Wsv[tid + 256 * i] = Wv[tid + 256 * i];
    }

    int lane = tid & 63;
    int w = tid >> 6;
    int g = lane >> 3, sl = lane & 7, gb = g << 3;
    int nodeLocal = w * 8 + g;
    int v = blockIdx.x * 32 + nodeLocal;  // N_NODES = 3125*32 exactly
    int beg = rowptr[v], end = rowptr[v + 1];

    float acc[8], ac2[8];
#pragma unroll
    for (int i = 0; i < 8; ++i) { acc[i] = 0.f; ac2[i] = 0.f; }
    {   // self row
        uint4 rw = ((const uint4*)(Hn + (size_t)v * 64))[sl];
        addpack4(acc, rw);
    }
    int t0 = beg;
    for (; t0 + 8 <= end; t0 += 8) {
        int sv = colsrc[t0 + sl];
        uint4 r[8];
#pragma unroll
        for (int t = 0; t < 8; ++t) {
            int s = __shfl(sv, gb + t);
            r[t] = ((const uint4*)(Hn + (size_t)s * 64))[sl];
        }
#pragma unroll
        for (int t = 0; t < 8; t += 2) {
            addpack4(acc, r[t]);
            addpack4(ac2, r[t + 1]);
        }
    }
    if (t0 < end) {
        int sv = (t0 + sl < end) ? colsrc[t0 + sl] : 0;
        int cnt = end - t0;
        int t = 0;
        for (; t + 2 <= cnt; t += 2) {
            int s0 = __shfl(sv, gb + t);
            int s1 = __shfl(sv, gb + t + 1);
            uint4 r0 = ((const uint4*)(Hn + (size_t)s0 * 64))[sl];
            uint4 r1 = ((const uint4*)(Hn + (size_t)s1 * 64))[sl];
            addpack4(acc, r0);
            addpack4(ac2, r1);
        }
        if (t < cnt) {
            int s0 = __shfl(sv, gb + t);
            uint4 r0 = ((const uint4*)(Hn + (size_t)s0 * 64))[sl];
            addpack4(acc, r0);
        }
    }
    float dv = dinv[v];
    float4 b0 = ((const float4*)(bias + sl * 8))[0];
    float4 b1v = ((const float4*)(bias + sl * 8))[1];
    float o[8];
    o[0] = (acc[0] + ac2[0]) * dv + b0.x;  o[1] = (acc[1] + ac2[1]) * dv + b0.y;
    o[2] = (acc[2] + ac2[2]) * dv + b0.z;  o[3] = (acc[3] + ac2[3]) * dv + b0.w;
    o[4] = (acc[4] + ac2[4]) * dv + b1v.x; o[5] = (acc[5] + ac2[5]) * dv + b1v.y;
    o[6] = (acc[6] + ac2[6]) * dv + b1v.z; o[7] = (acc[7] + ac2[7]) * dv + b1v.w;
#pragma unroll
    for (int i = 0; i < 8; ++i) o[i] = o[i] > 0.f ? o[i] : NEG_SLOPE * o[i];
    *(float4*)&R[nodeLocal][sl * 8] = make_float4(o[0], o[1], o[2], o[3]);
    *(float4*)&R[nodeLocal][sl * 8 + 4] = make_float4(o[4], o[5], o[6], o[7]);
    __syncthreads();

    // 32x32 W2 tile: thread = 1 row x 4 cols
    int row = tid >> 3;
    int c4 = (tid & 7) * 4;
    float a[4] = {};
#pragma unroll 8
    for (int k = 0; k < 64; ++k) {
        float x = R[row][k];
        float4 wv = *(const float4*)&W2s[k][c4];
        a[0] += x * wv.x; a[1] += x * wv.y; a[2] += x * wv.z; a[3] += x * wv.w;
    }
    int gv = blockIdx.x * 32 + row;
    float dv2 = dinv[gv];
    unsigned int lo = (unsigned int)f2bf(a[0] * dv2) | ((unsigned int)f2bf(a[1] * dv2) << 16);
    unsigned int hi = (unsigned int)f2bf(a[2] * dv2) | ((unsigned int)f2bf(a[3] * dv2) << 16);
    *(uint2*)(h2n + (size_t)gv * 32 + c4) = make_uint2(lo, hi);
}

// ---------------- gather32: node-per-group, 8-deep load batching ----------------
__global__ __launch_bounds__(256) void gather32_kernel(
    const unsigned short* __restrict__ Hn, const int* __restrict__ rowptr,
    const int* __restrict__ colsrc, const float* __restrict__ dinv,
    const float* __restrict__ bias, float* __restrict__ out) {
    int gwid = (blockIdx.x * blockDim.x + threadIdx.x) >> 6;
    int lane = threadIdx.x & 63;
    int g = lane >> 3, sl = lane & 7, gb = g << 3;
    int v = gwid * 8 + g;
    if (v >= N_NODES) return;
    int beg = rowptr[v], end = rowptr[v + 1];

    float acc[4], ac2[4];
#pragma unroll
    for (int i = 0; i < 4; ++i) { acc[i] = 0.f; ac2[i] = 0.f; }
    {   // self row
        uint2 rw = ((const uint2*)(Hn + (size_t)v * 32))[sl];
        addpack2(acc, rw);
    }
    int t0 = beg;
    for (; t0 + 8 <= end; t0 += 8) {
        int sv = colsrc[t0 + sl];
        uint2 r[8];
#pragma unroll
        for (int t = 0; t < 8; ++t) {
            int s = __shfl(sv, gb + t);
            r[t] = ((const uint2*)(Hn + (size_t)s * 32))[sl];
        }
#pragma unroll
        for (int t = 0; t < 8; t += 2) {
            addpack2(acc, r[t]);
            addpack2(ac2, r[t + 1]);
        }
    }
    if (t0 < end) {
        int sv = (t0 + sl < end) ? colsrc[t0 + sl] : 0;
        int cnt = end - t0;
        int t = 0;
        for (; t + 2 <= cnt; t += 2) {
            int s0 = __shfl(sv, gb + t);
            int s1 = __shfl(sv, gb + t + 1);
            uint2 r0 = ((const uint2*)(Hn + (size_t)s0 * 32))[sl];
            uint2 r1 = ((const uint2*)(Hn + (size_t)s1 * 32))[sl];
            addpack2(acc, r0);
            addpack2(ac2, r1);
        }
        if (t < cnt) {
            int s0 = __shfl(sv, gb + t);
            uint2 r0 = ((const uint2*)(Hn + (size_t)s0 * 32))[sl];
            addpack2(acc, r0);
        }
    }
    float dv = dinv[v];
    float4 bb = ((const float4*)bias)[sl];
    float o0 = (acc[0] + ac2[0]) * dv + bb.x;
    float o1 = (acc[1] + ac2[1]) * dv + bb.y;
    float o2 = (acc[2] + ac2[2]) * dv + bb.z;
    float o3 = (acc[3] + ac2[3]) * dv + bb.w;
    *(float4*)(out + (size_t)v * 32 + sl * 4) = make_float4(o0, o1, o2, o3);
}

extern "C" void kernel_launch(void* const* d_in, const int* in_sizes, int n_in,
                              void* d_out, int out_size, void* d_ws, size_t ws_size,
                              hipStream_t stream) {
    const float* x = (const float*)d_in[0];
    const int* ei = (const int*)d_in[1];  // [2,E]: src row then dst row
    const float* W1 = (const float*)d_in[2];
    const float* b1 = (const float*)d_in[3];
    const float* W2 = (const float*)d_in[4];
    const float* b2 = (const float*)d_in[5];
    float* out = (float*)d_out;

    const int* src = ei;
    const int* dst = ei + N_EDGES;

    // workspace layout, each region 256B-aligned (~36 MB)
    char* p = (char*)d_ws;
    auto alloc = [&](size_t bytes) { char* r = p; p += (bytes + 255) & ~(size_t)255; return r; };
    float* dinv = (float*)alloc(N_NODES * 4);
    int* rowptr = (int*)alloc((N_NODES + 1) * 4);
    int* bucketfill = (int*)alloc(NBUCK * 4);
    int* colsrc = (int*)alloc((size_t)N_EDGES * 4);
    unsigned short* h1n = (unsigned short*)alloc((size_t)N_NODES * DIN * 2);
    unsigned short* h2n = (unsigned short*)alloc((size_t)N_NODES * DOUT * 2);
    unsigned int* staging2 = (unsigned int*)alloc((size_t)NBUCK * CAP * 4);

    // CSR build
    hipMemsetAsync(bucketfill, 0, NBUCK * sizeof(int), stream);
    binpass1_kernel<<<NB1, 256, 0, stream>>>(src, dst, bucketfill, staging2);
    binpass2_kernel<<<NBUCK, 1024, 0, stream>>>(staging2, bucketfill, rowptr, dinv, colsrc);

    // layer 1 GEMM
    gemm_k64_n64_kernel<<<(N_NODES + 63) / 64, 256, 0, stream>>>(x, W1, dinv, h1n);

    // fused: gather layer1 + bias/leaky + W2 matmul + dinv pre-fold -> h2n
    gather64_fused_kernel<<<N_NODES / 32, 256, 0, stream>>>(
        h1n, rowptr, colsrc, dinv, b1, W2, h2n);

    // layer 2 aggregation -> final output
    gather32_kernel<<<(N_NODES / 8 * 64) / 256, 256, 0, stream>>>(
        h2n, rowptr, colsrc, dinv, b2, out);
}